// Round 1
// baseline (5541.823 us; speedup 1.0000x reference)
//
#include <hip/hip_runtime.h>

// SO(2)-equivariant edge conv, fp32 baseline.
// K=25 spherical comps, KR=19 m-primary rows, C=H=64, c_in1=128.
// Row layout (19): [0..4]=m0 l=0..4 | [5..8]=m1 re | [9..12]=m1 im | [13..15]=m2 re | [16..18]=m2 im

#define TE 8   // edges per workgroup

__device__ __forceinline__ float sigm_(float x){ return 1.0f/(1.0f+__expf(-x)); }
__device__ __forceinline__ float silu_(float x){ return x/(1.0f+__expf(-x)); }

#define CFMA(are, aie, xr_, xi_, wr_, wi_) \
    do { (are) = fmaf((xr_), (wr_), (are)); (are) = fmaf(-(xi_), (wi_), (are)); \
         (aie) = fmaf((xi_), (wr_), (aie)); (aie) = fmaf((xr_), (wi_), (aie)); } while(0)

// K1: gather + wigner rotate + radial MLP scale + SO2 conv1 + gate  -> y1g [chunk,19,64]
__global__ __launch_bounds__(256, 2)
void so2_k1(const float* __restrict__ nf, const float* __restrict__ ee,
            const float* __restrict__ wig,
            const float* __restrict__ rw1, const float* __restrict__ rb1,
            const float* __restrict__ rw2, const float* __restrict__ rb2,
            const float* __restrict__ wm0, const float* __restrict__ bm0,
            const float* __restrict__ wr1, const float* __restrict__ wi1,
            const float* __restrict__ wr2, const float* __restrict__ wi2,
            const int* __restrict__ snd, const int* __restrict__ rcv,
            float* __restrict__ y1g, int ebase)
{
    __shared__ float s_h[TE][64];      // radial hidden (post-silu)
    __shared__ float s_rad[TE][640];   // radial weights slice for current m
    __shared__ float s_x[TE][1024];    // rotated+scaled input rows for current m
    __shared__ float s_g[TE][256];     // raw gating logits (from m0 phase)
    __shared__ float s_wg[TE][200];    // wigner rows for current m
    __shared__ int   s_nd[TE][2];

    const int  t  = threadIdx.x;
    const int  e0 = ebase + blockIdx.x * TE;   // global edge base
    const long eo = (long)blockIdx.x * TE;     // ws-chunk-local edge base

    if (t < 2*TE) {
        int e = t >> 1;
        s_nd[e][t & 1] = (t & 1) ? rcv[e0 + e] : snd[e0 + e];
    }

    // radial hidden: h = silu(ee @ rw1 + rb1)
    for (int i = t; i < TE*64; i += 256) {
        int e = i >> 6, d = i & 63;
        float a = rb1[d];
        const float* eb = ee + (long)(e0 + e) * 128;
        #pragma unroll 8
        for (int dd = 0; dd < 128; ++dd) a = fmaf(eb[dd], rw1[dd*64 + d], a);
        s_h[e][d] = silu_(a);
    }
    __syncthreads();

    auto rad_slice = [&](int off, int len) {   // s_rad[e][0..len) = h @ rw2[:, off..off+len) + rb2
        for (int e = 0; e < TE; ++e)
            for (int idx = t; idx < len; idx += 256) {
                float a = rb2[off + idx];
                #pragma unroll 8
                for (int d = 0; d < 64; ++d)
                    a = fmaf(s_h[e][d], rw2[d*1536 + off + idx], a);
                s_rad[e][idx] = a;
            }
    };
    auto wig_stage = [&](int row0, int n25) {  // n25 = nrows*25 (<=200)
        for (int e = 0; e < TE; ++e)
            if (t < n25) s_wg[e][t] = wig[(long)(e0 + e)*475 + row0*25 + t];
    };
    auto x_stage = [&](int nrows, int radmod) { // s_x[e][r*128+c] = (wig_rows @ msg) * rad
        for (int i = t; i < TE*128; i += 256) {
            int e = i >> 7, c = i & 127;
            const float* npt = nf + (long)s_nd[e][c >> 6] * 1600 + (c & 63);
            float m[25];
            #pragma unroll
            for (int k = 0; k < 25; ++k) m[k] = npt[k*64];
            for (int r = 0; r < nrows; ++r) {
                float a = 0.f;
                #pragma unroll
                for (int k = 0; k < 25; ++k) a = fmaf(s_wg[e][r*25 + k], m[k], a);
                int rm = (r >= radmod) ? r - radmod : r;
                s_x[e][r*128 + c] = a * s_rad[e][rm*128 + c];
            }
        }
    };

    // ================= m = 0 (rows 0..4, K=640, N=576 incl. 256 gating) =================
    rad_slice(0, 640);
    wig_stage(0, 125);
    __syncthreads();
    x_stage(5, 5);
    __syncthreads();

    {   // gating columns j = 320 + t
        float a[TE];
        #pragma unroll
        for (int e = 0; e < TE; ++e) a[e] = 0.f;
        const float* wp = wm0 + 320 + t;
        for (int k4 = 0; k4 < 160; ++k4) {
            float w0 = wp[(4*k4+0)*576], w1 = wp[(4*k4+1)*576];
            float w2 = wp[(4*k4+2)*576], w3 = wp[(4*k4+3)*576];
            #pragma unroll
            for (int e = 0; e < TE; ++e) {
                float4 x = ((const float4*)s_x[e])[k4];
                a[e] = fmaf(x.x, w0, a[e]); a[e] = fmaf(x.y, w1, a[e]);
                a[e] = fmaf(x.z, w2, a[e]); a[e] = fmaf(x.w, w3, a[e]);
            }
        }
        #pragma unroll
        for (int e = 0; e < TE; ++e) s_g[e][t] = a[e] + bm0[320 + t];
    }
    __syncthreads();

    for (int j = t; j < 320; j += 256) {       // out columns, gate fused
        float a[TE];
        #pragma unroll
        for (int e = 0; e < TE; ++e) a[e] = 0.f;
        const float* wp = wm0 + j;
        for (int k4 = 0; k4 < 160; ++k4) {
            float w0 = wp[(4*k4+0)*576], w1 = wp[(4*k4+1)*576];
            float w2 = wp[(4*k4+2)*576], w3 = wp[(4*k4+3)*576];
            #pragma unroll
            for (int e = 0; e < TE; ++e) {
                float4 x = ((const float4*)s_x[e])[k4];
                a[e] = fmaf(x.x, w0, a[e]); a[e] = fmaf(x.y, w1, a[e]);
                a[e] = fmaf(x.z, w2, a[e]); a[e] = fmaf(x.w, w3, a[e]);
            }
        }
        float b = bm0[j];
        if (j < 64) {          // row 0 (l=0): silu
            #pragma unroll
            for (int e = 0; e < TE; ++e)
                y1g[(eo + e)*1216 + j] = silu_(a[e] + b);
        } else {               // rows 1..4: sigmoid gate, g idx = (l-1)*64+c = j-64
            #pragma unroll
            for (int e = 0; e < TE; ++e)
                y1g[(eo + e)*1216 + j] = (a[e] + b) * sigm_(s_g[e][j - 64]);
        }
    }
    __syncthreads();

    // ================= m = 1 (rows 5..12, K=512, N=256) =================
    rad_slice(640, 512);
    wig_stage(5, 200);
    __syncthreads();
    x_stage(8, 4);
    __syncthreads();

    {
        float ar[TE], ai[TE];
        #pragma unroll
        for (int e = 0; e < TE; ++e) { ar[e] = 0.f; ai[e] = 0.f; }
        const float* wpr = wr1 + t;
        const float* wpi = wi1 + t;
        for (int k4 = 0; k4 < 128; ++k4) {
            float wr_[4], wi_[4];
            #pragma unroll
            for (int q = 0; q < 4; ++q) { wr_[q] = wpr[(4*k4+q)*256]; wi_[q] = wpi[(4*k4+q)*256]; }
            #pragma unroll
            for (int e = 0; e < TE; ++e) {
                float4 xr = ((const float4*)s_x[e])[k4];
                float4 xi = ((const float4*)(s_x[e] + 512))[k4];
                CFMA(ar[e], ai[e], xr.x, xi.x, wr_[0], wi_[0]);
                CFMA(ar[e], ai[e], xr.y, xi.y, wr_[1], wi_[1]);
                CFMA(ar[e], ai[e], xr.z, xi.z, wr_[2], wi_[2]);
                CFMA(ar[e], ai[e], xr.w, xi.w, wr_[3], wi_[3]);
            }
        }
        #pragma unroll
        for (int e = 0; e < TE; ++e) {
            float g = sigm_(s_g[e][t]);                 // l-1 = t>>6
            y1g[(eo + e)*1216 + 320 + t] = ar[e] * g;
            y1g[(eo + e)*1216 + 576 + t] = ai[e] * g;
        }
    }
    __syncthreads();

    // ================= m = 2 (rows 13..18, K=384, N=192) =================
    rad_slice(1152, 384);
    wig_stage(13, 150);
    __syncthreads();
    x_stage(6, 3);
    __syncthreads();

    if (t < 192) {
        float ar[TE], ai[TE];
        #pragma unroll
        for (int e = 0; e < TE; ++e) { ar[e] = 0.f; ai[e] = 0.f; }
        const float* wpr = wr2 + t;
        const float* wpi = wi2 + t;
        for (int k4 = 0; k4 < 96; ++k4) {
            float wr_[4], wi_[4];
            #pragma unroll
            for (int q = 0; q < 4; ++q) { wr_[q] = wpr[(4*k4+q)*192]; wi_[q] = wpi[(4*k4+q)*192]; }
            #pragma unroll
            for (int e = 0; e < TE; ++e) {
                float4 xr = ((const float4*)s_x[e])[k4];
                float4 xi = ((const float4*)(s_x[e] + 384))[k4];
                CFMA(ar[e], ai[e], xr.x, xi.x, wr_[0], wi_[0]);
                CFMA(ar[e], ai[e], xr.y, xi.y, wr_[1], wi_[1]);
                CFMA(ar[e], ai[e], xr.z, xi.z, wr_[2], wi_[2]);
                CFMA(ar[e], ai[e], xr.w, xi.w, wr_[3], wi_[3]);
            }
        }
        #pragma unroll
        for (int e = 0; e < TE; ++e) {
            float g = sigm_(s_g[e][64 + t]);            // l-1 = (64+t)>>6
            y1g[(eo + e)*1216 + 832 + t]  = ar[e] * g;
            y1g[(eo + e)*1216 + 1024 + t] = ai[e] * g;
        }
    }
}

// K2: SO2 conv2 (in-place in LDS) + envelope + wigner_inv + atomic scatter-add
__global__ __launch_bounds__(256, 2)
void so2_k2(const float* __restrict__ y1g,
            const float* __restrict__ winv, const float* __restrict__ env,
            const float* __restrict__ wm0, const float* __restrict__ bm0,
            const float* __restrict__ wr1, const float* __restrict__ wi1,
            const float* __restrict__ wr2, const float* __restrict__ wi2,
            const int* __restrict__ rcv, float* __restrict__ out, int ebase)
{
    __shared__ float s_x[TE][1216];    // gated conv1 output, overwritten phase-by-phase with conv2 output
    __shared__ float s_wv[TE][475];    // wigner_inv tile

    const int  t  = threadIdx.x;
    const int  e0 = ebase + blockIdx.x * TE;
    const long eo = (long)blockIdx.x * TE;

    {
        float4* sf = (float4*)&s_x[0][0];
        const float4* gs = (const float4*)(y1g + eo*1216);
        for (int i = t; i < TE*304; i += 256) sf[i] = gs[i];
        for (int e = 0; e < TE; ++e)
            for (int idx = t; idx < 475; idx += 256)
                s_wv[e][idx] = winv[(long)(e0 + e)*475 + idx];
    }
    __syncthreads();

    // m0: K=320 -> N=320 (rows 0..4, flat [0,320))
    float r0[TE], r1[TE];
    {
        #pragma unroll
        for (int e = 0; e < TE; ++e) r0[e] = bm0[t];
        const float* wp = wm0 + t;
        for (int k4 = 0; k4 < 80; ++k4) {
            float w0 = wp[(4*k4+0)*320], w1 = wp[(4*k4+1)*320];
            float w2 = wp[(4*k4+2)*320], w3 = wp[(4*k4+3)*320];
            #pragma unroll
            for (int e = 0; e < TE; ++e) {
                float4 x = ((const float4*)s_x[e])[k4];
                r0[e] = fmaf(x.x, w0, r0[e]); r0[e] = fmaf(x.y, w1, r0[e]);
                r0[e] = fmaf(x.z, w2, r0[e]); r0[e] = fmaf(x.w, w3, r0[e]);
            }
        }
        if (t < 64) {
            #pragma unroll
            for (int e = 0; e < TE; ++e) r1[e] = bm0[256 + t];
            const float* wp2 = wm0 + 256 + t;
            for (int k4 = 0; k4 < 80; ++k4) {
                float w0 = wp2[(4*k4+0)*320], w1 = wp2[(4*k4+1)*320];
                float w2 = wp2[(4*k4+2)*320], w3 = wp2[(4*k4+3)*320];
                #pragma unroll
                for (int e = 0; e < TE; ++e) {
                    float4 x = ((const float4*)s_x[e])[k4];
                    r1[e] = fmaf(x.x, w0, r1[e]); r1[e] = fmaf(x.y, w1, r1[e]);
                    r1[e] = fmaf(x.z, w2, r1[e]); r1[e] = fmaf(x.w, w3, r1[e]);
                }
            }
        }
    }
    __syncthreads();
    #pragma unroll
    for (int e = 0; e < TE; ++e) s_x[e][t] = r0[e];
    if (t < 64) {
        #pragma unroll
        for (int e = 0; e < TE; ++e) s_x[e][256 + t] = r1[e];
    }

    // m1: K=256 -> N=256 (reads/writes flat [320,832); disjoint from m0's writes)
    {
        float ar[TE], ai[TE];
        #pragma unroll
        for (int e = 0; e < TE; ++e) { ar[e] = 0.f; ai[e] = 0.f; }
        const float* wpr = wr1 + t;
        const float* wpi = wi1 + t;
        for (int k4 = 0; k4 < 64; ++k4) {
            float wr_[4], wi_[4];
            #pragma unroll
            for (int q = 0; q < 4; ++q) { wr_[q] = wpr[(4*k4+q)*256]; wi_[q] = wpi[(4*k4+q)*256]; }
            #pragma unroll
            for (int e = 0; e < TE; ++e) {
                float4 xr = ((const float4*)(s_x[e] + 320))[k4];
                float4 xi = ((const float4*)(s_x[e] + 576))[k4];
                CFMA(ar[e], ai[e], xr.x, xi.x, wr_[0], wi_[0]);
                CFMA(ar[e], ai[e], xr.y, xi.y, wr_[1], wi_[1]);
                CFMA(ar[e], ai[e], xr.z, xi.z, wr_[2], wi_[2]);
                CFMA(ar[e], ai[e], xr.w, xi.w, wr_[3], wi_[3]);
            }
        }
        __syncthreads();   // all reads of [320,832) done before overwrite
        #pragma unroll
        for (int e = 0; e < TE; ++e) { s_x[e][320 + t] = ar[e]; s_x[e][576 + t] = ai[e]; }
    }

    // m2: K=192 -> N=192 (flat [832,1216))
    {
        float br[TE], bi[TE];
        if (t < 192) {
            #pragma unroll
            for (int e = 0; e < TE; ++e) { br[e] = 0.f; bi[e] = 0.f; }
            const float* wpr = wr2 + t;
            const float* wpi = wi2 + t;
            for (int k4 = 0; k4 < 48; ++k4) {
                float wr_[4], wi_[4];
                #pragma unroll
                for (int q = 0; q < 4; ++q) { wr_[q] = wpr[(4*k4+q)*192]; wi_[q] = wpi[(4*k4+q)*192]; }
                #pragma unroll
                for (int e = 0; e < TE; ++e) {
                    float4 xr = ((const float4*)(s_x[e] + 832))[k4];
                    float4 xi = ((const float4*)(s_x[e] + 1024))[k4];
                    CFMA(br[e], bi[e], xr.x, xi.x, wr_[0], wi_[0]);
                    CFMA(br[e], bi[e], xr.y, xi.y, wr_[1], wi_[1]);
                    CFMA(br[e], bi[e], xr.z, xi.z, wr_[2], wi_[2]);
                    CFMA(br[e], bi[e], xr.w, xi.w, wr_[3], wi_[3]);
                }
            }
        }
        __syncthreads();
        if (t < 192) {
            #pragma unroll
            for (int e = 0; e < TE; ++e) { s_x[e][832 + t] = br[e]; s_x[e][1024 + t] = bi[e]; }
        }
    }
    __syncthreads();

    // envelope * (wigner_inv @ Y2) -> atomic scatter-add into out[receiver]
    for (int e = 0; e < TE; ++e) {
        const float ev  = env[e0 + e];
        const int node  = rcv[e0 + e];
        float* ob = out + (long)node * 1600;
        for (int f = t; f < 1600; f += 256) {
            int r = f >> 6, c = f & 63;
            float a = 0.f;
            #pragma unroll
            for (int k = 0; k < 19; ++k)
                a = fmaf(s_wv[e][r*19 + k], s_x[e][k*64 + c], a);
            atomicAdd(ob + f, a * ev);
        }
    }
}

extern "C" void kernel_launch(void* const* d_in, const int* in_sizes, int n_in,
                              void* d_out, int out_size, void* d_ws, size_t ws_size,
                              hipStream_t stream)
{
    const float* nf   = (const float*)d_in[0];
    const float* ee   = (const float*)d_in[1];
    const float* wig  = (const float*)d_in[2];
    const float* winv = (const float*)d_in[3];
    const float* env  = (const float*)d_in[4];
    const float* rw1  = (const float*)d_in[5];
    const float* rb1  = (const float*)d_in[6];
    const float* rw2  = (const float*)d_in[7];
    const float* rb2  = (const float*)d_in[8];
    const float* w1m0 = (const float*)d_in[9];
    const float* b1m0 = (const float*)d_in[10];
    const float* w1r1 = (const float*)d_in[11];
    const float* w1i1 = (const float*)d_in[12];
    const float* w1r2 = (const float*)d_in[13];
    const float* w1i2 = (const float*)d_in[14];
    const float* w2m0 = (const float*)d_in[15];
    const float* b2m0 = (const float*)d_in[16];
    const float* w2r1 = (const float*)d_in[17];
    const float* w2i1 = (const float*)d_in[18];
    const float* w2r2 = (const float*)d_in[19];
    const float* w2i2 = (const float*)d_in[20];
    const int*   snd  = (const int*)d_in[21];
    const int*   rcv  = (const int*)d_in[22];
    float* out = (float*)d_out;
    float* y1g = (float*)d_ws;

    const long E = in_sizes[21];          // 50000, multiple of TE

    // segment_sum accumulates via atomics -> zero output every call
    hipMemsetAsync(d_out, 0, (size_t)out_size * sizeof(float), stream);

    // chunk edges so the [chunk,19,64] f32 intermediate fits whatever ws we got
    long cap   = (long)(ws_size / (1216 * sizeof(float)));
    long chunk = (cap / TE) * TE;
    if (chunk > E)  chunk = E;
    if (chunk < TE) chunk = TE;
    for (long base = 0; base < E; base += chunk) {
        long n = E - base; if (n > chunk) n = chunk;
        int nb = (int)(n / TE);
        so2_k1<<<nb, 256, 0, stream>>>(nf, ee, wig, rw1, rb1, rw2, rb2,
                                       w1m0, b1m0, w1r1, w1i1, w1r2, w1i2,
                                       snd, rcv, y1g, (int)base);
        so2_k2<<<nb, 256, 0, stream>>>(y1g, winv, env, w2m0, b2m0,
                                       w2r1, w2i1, w2r2, w2i2,
                                       rcv, out, (int)base);
    }
    (void)n_in;
}

// Round 2
// 2059.063 us; speedup vs baseline: 2.6914x; 2.6914x over previous
//
#include <hip/hip_runtime.h>

// SO(2)-equivariant edge conv — bf16 MFMA pipeline.
// Layout facts: K=25 sph comps, KR=19 m-rows, C=H=64, c_in1=128.
// X per edge (2432 bf16): m0 rows0-4 [0,640) | m1 re+im rows5-12 [640,1664) | m2 [1664,2432)
// Z/Y2 per edge (1216 bf16): m0 [0,320) | m1 [320,832) | m2 [832,1216)
// Weights prepped transposed [N][K] bf16; complex convs combined: W=[[wr,wi],[-wi,wr]].

typedef __attribute__((ext_vector_type(8))) short bf16x8;
typedef __attribute__((ext_vector_type(4))) float f32x4;

__device__ __forceinline__ unsigned short f2b(float f) {
    unsigned u = __float_as_uint(f);
    unsigned r = (u + 0x7FFFu + ((u >> 16) & 1u)) >> 16;
    return (unsigned short)r;
}
__device__ __forceinline__ float b2f(unsigned short h) {
    return __uint_as_float(((unsigned)h) << 16);
}
__device__ __forceinline__ float sigm_(float x){ return 1.0f/(1.0f+__expf(-x)); }
__device__ __forceinline__ float silu_(float x){ return x/(1.0f+__expf(-x)); }

// weight region offsets (bf16 elems) in ws
#define OFF_W1T   0L
#define OFF_W1C1  368640L
#define OFF_W1C2  892928L
#define OFF_V0T   1187840L
#define OFF_V1C   1290240L
#define OFF_V2C   1552384L
#define OFF_RW2T  1699840L
#define W_TOTAL   1798144L

// ---------------- weight prep: f32 -> bf16, transpose to [N][K], fold complex ----
__global__ void k_prep(const float* __restrict__ w1m0, const float* __restrict__ w1r1,
                       const float* __restrict__ w1i1, const float* __restrict__ w1r2,
                       const float* __restrict__ w1i2, const float* __restrict__ w2m0,
                       const float* __restrict__ w2r1, const float* __restrict__ w2i1,
                       const float* __restrict__ w2r2, const float* __restrict__ w2i2,
                       const float* __restrict__ rw2, short* __restrict__ W)
{
    long i = (long)blockIdx.x * blockDim.x + threadIdx.x;
    if (i >= W_TOTAL) return;
    float v;
    if (i < OFF_W1C1) {                    // W1T [576][640]
        long n = i / 640, k = i - n * 640;
        v = w1m0[k * 576 + n];
    } else if (i < OFF_W1C2) {             // W1c1 [512][1024]
        long j = i - OFF_W1C1; int n = (int)(j >> 10), k = (int)(j & 1023);
        v = (n < 256) ? ((k < 512) ? w1r1[k*256 + n] : -w1i1[(k-512)*256 + n])
                      : ((k < 512) ? w1i1[k*256 + (n-256)] : w1r1[(k-512)*256 + (n-256)]);
    } else if (i < OFF_V0T) {              // W1c2 [384][768]
        long j = i - OFF_W1C2; int n = (int)(j / 768), k = (int)(j - (long)n * 768);
        v = (n < 192) ? ((k < 384) ? w1r2[k*192 + n] : -w1i2[(k-384)*192 + n])
                      : ((k < 384) ? w1i2[k*192 + (n-192)] : w1r2[(k-384)*192 + (n-192)]);
    } else if (i < OFF_V1C) {              // V0T [320][320]
        long j = i - OFF_V0T; int n = (int)(j / 320), k = (int)(j - (long)n * 320);
        v = w2m0[k * 320 + n];
    } else if (i < OFF_V2C) {              // V1c [512][512]
        long j = i - OFF_V1C; int n = (int)(j >> 9), k = (int)(j & 511);
        v = (n < 256) ? ((k < 256) ? w2r1[k*256 + n] : -w2i1[(k-256)*256 + n])
                      : ((k < 256) ? w2i1[k*256 + (n-256)] : w2r1[(k-256)*256 + (n-256)]);
    } else if (i < OFF_RW2T) {             // V2c [384][384]
        long j = i - OFF_V2C; int n = (int)(j / 384), k = (int)(j - (long)n * 384);
        v = (n < 192) ? ((k < 192) ? w2r2[k*192 + n] : -w2i2[(k-192)*192 + n])
                      : ((k < 192) ? w2i2[k*192 + (n-192)] : w2r2[(k-192)*192 + (n-192)]);
    } else {                               // RW2T [1536][64]
        long j = i - OFF_RW2T; int n = (int)(j >> 6), d = (int)(j & 63);
        v = rw2[d * 1536 + n];
    }
    W[i] = (short)f2b(v);
}

// ---------------- radial MLP: h = silu(ee@rw1+rb1) [VALU]; rad = h@rw2+rb2 [MFMA] ----
__global__ __launch_bounds__(512)
void k_rad(const float* __restrict__ ee, const float* __restrict__ rw1,
           const float* __restrict__ rb1, const float* __restrict__ rb2,
           const short* __restrict__ RW2T, short* __restrict__ rad,
           long e0, long Etot)
{
    __shared__ __align__(16) short s_h[32 * 64];   // rows 128B, XOR-swizzled
    const int t = threadIdx.x, w = t >> 6, l = t & 63, l15 = l & 15, lhi = l >> 4;
    const long eb = (long)blockIdx.x * 32;

    #pragma unroll
    for (int j = 0; j < 4; ++j) {
        int i = t + j * 512;
        int e = i >> 6, d = i & 63;
        long ge = e0 + eb + e;
        float a = rb1[d];
        if (ge < Etot) {
            const float* ep = ee + ge * 128;
            #pragma unroll 16
            for (int dd = 0; dd < 128; ++dd) a = fmaf(ep[dd], rw1[dd * 64 + d], a);
            a = silu_(a);
        } else a = 0.f;
        *(short*)((char*)s_h + e * 128 + ((d * 2) ^ ((e & 7) << 4))) = (short)f2b(a);
    }
    __syncthreads();

    f32x4 acc[6][2][2];
    #pragma unroll
    for (int g = 0; g < 6; ++g)
        #pragma unroll
        for (int mt = 0; mt < 2; ++mt)
            #pragma unroll
            for (int nt = 0; nt < 2; ++nt)
                acc[g][mt][nt] = (f32x4){0.f, 0.f, 0.f, 0.f};

    #pragma unroll
    for (int ks = 0; ks < 2; ++ks) {
        bf16x8 af[2];
        #pragma unroll
        for (int mt = 0; mt < 2; ++mt)
            af[mt] = *(const bf16x8*)((const char*)s_h + (mt * 16 + l15) * 128 +
                                      (((ks << 6) + (lhi << 4)) ^ ((l & 7) << 4)));
        #pragma unroll
        for (int g = 0; g < 6; ++g) {
            int grp = w + g * 8;                       // 0..47, all valid
            #pragma unroll
            for (int nt = 0; nt < 2; ++nt) {
                int col = grp * 32 + nt * 16 + l15;
                bf16x8 bf = *(const bf16x8*)(RW2T + (long)col * 64 + (ks << 5) + (lhi << 3));
                #pragma unroll
                for (int mt = 0; mt < 2; ++mt)
                    acc[g][mt][nt] = __builtin_amdgcn_mfma_f32_16x16x32_bf16(af[mt], bf, acc[g][mt][nt], 0, 0, 0);
            }
        }
    }
    #pragma unroll
    for (int g = 0; g < 6; ++g)
        #pragma unroll
        for (int nt = 0; nt < 2; ++nt) {
            int col = (w + g * 8) * 32 + nt * 16 + l15;
            float bias = rb2[col];
            #pragma unroll
            for (int mt = 0; mt < 2; ++mt)
                #pragma unroll
                for (int r = 0; r < 4; ++r) {
                    int e = mt * 16 + lhi * 4 + r;
                    rad[(eb + e) * 1536 + col] = (short)f2b(acc[g][mt][nt][r] + bias);
                }
        }
}

// ---------------- gather + wigner rotate (fp32) * rad -> X bf16 ----------------
__global__ void k_rot(const float* __restrict__ nf, const float* __restrict__ wig,
                      const short* __restrict__ rad,
                      const int* __restrict__ snd, const int* __restrict__ rcv,
                      short* __restrict__ X, long e0, long nchunk, long Etot)
{
    const int t = threadIdx.x;
    const long eb = (long)blockIdx.x * 8;
    #pragma unroll
    for (int j = 0; j < 4; ++j) {
        int i = t + j * 256;           // [0, 1024) = 8 edges x 128 cols
        int e = i >> 7, c = i & 127;
        long el = eb + e;
        short* xrow = X + el * 2432;
        if (el >= nchunk) {
            #pragma unroll
            for (int r = 0; r < 19; ++r) xrow[r * 128 + c] = 0;
            continue;
        }
        long ge = e0 + el;
        int node = (c < 64) ? snd[ge] : rcv[ge];
        const float* npt = nf + (long)node * 1600 + (c & 63);
        float m[25];
        #pragma unroll
        for (int k = 0; k < 25; ++k) m[k] = npt[k * 64];
        const float* wp = wig + ge * 475;
        const short* rp = rad + el * 1536;
        #pragma unroll
        for (int r = 0; r < 19; ++r) {
            float a = 0.f;
            #pragma unroll
            for (int k = 0; k < 25; ++k) a = fmaf(wp[r * 25 + k], m[k], a);
            int rr = (r < 9) ? r : ((r < 16) ? r - 4 : r - 7);
            a *= b2f((unsigned short)rp[rr * 128 + c]);
            xrow[r * 128 + c] = (short)f2b(a);
        }
    }
}

// ---------------- generic MFMA GEMM phase over one m-block ----------------
// A: [64 edges][Km] bf16 at Xp (+e*RS), staged to LDS in 256-k chunks (XOR-swizzled)
// B: W [Nm][Km] bf16 transposed, 16B frags direct from L2
// acc[g][mt][nt]: group g = wave + 8g (32 cols each), mt = edge tile, nt = 16-col tile
template<int NACC>
__device__ __forceinline__ void conv_phase(
    const short* __restrict__ Xp, long RS, int Km, int Nm,
    const short* __restrict__ W, short* s_x, int t, f32x4 (&acc)[NACC][4][2])
{
    const int w = t >> 6, l = t & 63, l15 = l & 15, lhi = l >> 4;
    const int swz = (l & 7) << 4;
    #pragma unroll
    for (int g = 0; g < NACC; ++g)
        #pragma unroll
        for (int mt = 0; mt < 4; ++mt)
            #pragma unroll
            for (int nt = 0; nt < 2; ++nt)
                acc[g][mt][nt] = (f32x4){0.f, 0.f, 0.f, 0.f};

    const int nch = (Km + 255) >> 8;
    uint4 ra[4], rb[4];
    {
        const int kw = (Km < 256) ? Km : 256;
        const int i8 = kw >> 3, sh = 31 - __clz(i8);
        #pragma unroll
        for (int j = 0; j < 4; ++j) {
            int p = t + j * 512;
            if (p < (i8 << 6)) {
                int e = p >> sh, k8 = p & (i8 - 1);
                ra[j] = *(const uint4*)(Xp + (long)e * RS + (k8 << 3));
            }
        }
    }
    for (int ch = 0; ch < nch; ++ch) {
        const int kc0 = ch << 8;
        const int kwv = Km - kc0;
        const int kw = (kwv < 256) ? kwv : 256;
        const int i8 = kw >> 3, sh = 31 - __clz(i8);
        __syncthreads();                    // prior reads of s_x done
        #pragma unroll
        for (int j = 0; j < 4; ++j) {
            int p = t + j * 512;
            if (p < (i8 << 6)) {
                int e = p >> sh, k8 = p & (i8 - 1);
                *(uint4*)((char*)s_x + e * 512 + ((k8 << 4) ^ ((e & 7) << 4))) = ra[j];
            }
        }
        if (ch + 1 < nch) {                 // T14: issue next chunk's loads early
            const int kc1 = kc0 + 256;
            const int kwv2 = Km - kc1;
            const int kw2 = (kwv2 < 256) ? kwv2 : 256;
            const int i82 = kw2 >> 3, sh2 = 31 - __clz(i82);
            #pragma unroll
            for (int j = 0; j < 4; ++j) {
                int p = t + j * 512;
                if (p < (i82 << 6)) {
                    int e = p >> sh2, k8 = p & (i82 - 1);
                    rb[j] = *(const uint4*)(Xp + (long)e * RS + kc1 + (k8 << 3));
                }
            }
        }
        __syncthreads();                    // s_x ready
        const int nks = kw >> 5;
        for (int ks = 0; ks < nks; ++ks) {
            bf16x8 af[4];
            #pragma unroll
            for (int mt = 0; mt < 4; ++mt)
                af[mt] = *(const bf16x8*)((const char*)s_x + (mt * 16 + l15) * 512 +
                                          (((ks << 6) + (lhi << 4)) ^ swz));
            #pragma unroll
            for (int g = 0; g < NACC; ++g) {
                const int grp = w + (g << 3);
                if ((grp << 5) < Nm) {
                    #pragma unroll
                    for (int nt = 0; nt < 2; ++nt) {
                        const int col = (grp << 5) + (nt << 4) + l15;
                        bf16x8 bf = *(const bf16x8*)(W + (long)col * Km + kc0 + (ks << 5) + (lhi << 3));
                        #pragma unroll
                        for (int mt = 0; mt < 4; ++mt)
                            acc[g][mt][nt] = __builtin_amdgcn_mfma_f32_16x16x32_bf16(af[mt], bf, acc[g][mt][nt], 0, 0, 0);
                    }
                }
            }
        }
        #pragma unroll
        for (int j = 0; j < 4; ++j) ra[j] = rb[j];
    }
}

// ---------------- conv1 + fused gate -> Z bf16 [E,1216] ----------------
__global__ __launch_bounds__(512)
void k_conv1(const short* __restrict__ X, const short* __restrict__ W0,
             const short* __restrict__ W1, const short* __restrict__ W2,
             const float* __restrict__ b1m0, short* __restrict__ Z)
{
    __shared__ __align__(16) short s_x[64 * 256];
    __shared__ __align__(16) short s_g[64 * 256];   // sigmoid gates, bf16
    const int t = threadIdx.x, w = t >> 6, l = t & 63, l15 = l & 15, lhi = l >> 4;
    const long eb = (long)blockIdx.x * 64;
    f32x4 acc[3][4][2];

    // ===== m0: K=640 -> N=576 (320 out + 256 gating) =====
    conv_phase<3>(X + eb * 2432, 2432, 640, 576, W0, s_x, t, acc);
    #pragma unroll
    for (int g = 0; g < 3; ++g) {
        int grp = w + g * 8;
        if (grp < 18) {
            #pragma unroll
            for (int nt = 0; nt < 2; ++nt) {
                int jj = grp * 32 + nt * 16 + l15;
                if (jj >= 320) {
                    float bias = b1m0[jj];
                    #pragma unroll
                    for (int mt = 0; mt < 4; ++mt)
                        #pragma unroll
                        for (int r = 0; r < 4; ++r) {
                            int e = mt * 16 + lhi * 4 + r;
                            s_g[e * 256 + (jj - 320)] = (short)f2b(sigm_(acc[g][mt][nt][r] + bias));
                        }
                }
            }
        }
    }
    __syncthreads();
    #pragma unroll
    for (int g = 0; g < 3; ++g) {
        int grp = w + g * 8;
        if (grp < 10) {
            #pragma unroll
            for (int nt = 0; nt < 2; ++nt) {
                int jj = grp * 32 + nt * 16 + l15;
                float bias = b1m0[jj];
                int r0 = jj >> 6;
                #pragma unroll
                for (int mt = 0; mt < 4; ++mt)
                    #pragma unroll
                    for (int r = 0; r < 4; ++r) {
                        int e = mt * 16 + lhi * 4 + r;
                        float v = acc[g][mt][nt][r] + bias;
                        float zv = (r0 == 0) ? silu_(v)
                                 : v * b2f((unsigned short)s_g[e * 256 + (r0 - 1) * 64 + (jj & 63)]);
                        Z[(eb + e) * 1216 + jj] = (short)f2b(zv);
                    }
            }
        }
    }

    // ===== m1: K=1024 -> N=512, gate idx = j & 255 =====
    conv_phase<3>(X + eb * 2432 + 640, 2432, 1024, 512, W1, s_x, t, acc);
    #pragma unroll
    for (int g = 0; g < 3; ++g) {
        int grp = w + g * 8;
        if (grp < 16) {
            #pragma unroll
            for (int nt = 0; nt < 2; ++nt) {
                int jj = grp * 32 + nt * 16 + l15;
                #pragma unroll
                for (int mt = 0; mt < 4; ++mt)
                    #pragma unroll
                    for (int r = 0; r < 4; ++r) {
                        int e = mt * 16 + lhi * 4 + r;
                        float gt = b2f((unsigned short)s_g[e * 256 + (jj & 255)]);
                        Z[(eb + e) * 1216 + 320 + jj] = (short)f2b(acc[g][mt][nt][r] * gt);
                    }
            }
        }
    }

    // ===== m2: K=768 -> N=384, gate idx = 64 + (j mod 192) =====
    conv_phase<3>(X + eb * 2432 + 1664, 2432, 768, 384, W2, s_x, t, acc);
    #pragma unroll
    for (int g = 0; g < 3; ++g) {
        int grp = w + g * 8;
        if (grp < 12) {
            #pragma unroll
            for (int nt = 0; nt < 2; ++nt) {
                int jj = grp * 32 + nt * 16 + l15;
                int jm = (jj >= 192) ? jj - 192 : jj;
                #pragma unroll
                for (int mt = 0; mt < 4; ++mt)
                    #pragma unroll
                    for (int r = 0; r < 4; ++r) {
                        int e = mt * 16 + lhi * 4 + r;
                        float gt = b2f((unsigned short)s_g[e * 256 + 64 + jm]);
                        Z[(eb + e) * 1216 + 832 + jj] = (short)f2b(acc[g][mt][nt][r] * gt);
                    }
            }
        }
    }
}

// ---------------- conv2 -> Y2 bf16 [E,1216] ----------------
__global__ __launch_bounds__(512)
void k_conv2(const short* __restrict__ Zin, const short* __restrict__ V0,
             const short* __restrict__ V1, const short* __restrict__ V2,
             const float* __restrict__ b2m0, short* __restrict__ Y2)
{
    __shared__ __align__(16) short s_x[64 * 256];
    const int t = threadIdx.x, w = t >> 6, l = t & 63, l15 = l & 15, lhi = l >> 4;
    const long eb = (long)blockIdx.x * 64;
    f32x4 acc[2][4][2];

    conv_phase<2>(Zin + eb * 1216, 1216, 320, 320, V0, s_x, t, acc);
    #pragma unroll
    for (int g = 0; g < 2; ++g) {
        int grp = w + g * 8;
        if (grp < 10) {
            #pragma unroll
            for (int nt = 0; nt < 2; ++nt) {
                int jj = grp * 32 + nt * 16 + l15;
                float bias = b2m0[jj];
                #pragma unroll
                for (int mt = 0; mt < 4; ++mt)
                    #pragma unroll
                    for (int r = 0; r < 4; ++r) {
                        int e = mt * 16 + lhi * 4 + r;
                        Y2[(eb + e) * 1216 + jj] = (short)f2b(acc[g][mt][nt][r] + bias);
                    }
            }
        }
    }
    conv_phase<2>(Zin + eb * 1216 + 320, 1216, 512, 512, V1, s_x, t, acc);
    #pragma unroll
    for (int g = 0; g < 2; ++g) {
        int grp = w + g * 8;
        if (grp < 16) {
            #pragma unroll
            for (int nt = 0; nt < 2; ++nt) {
                int jj = grp * 32 + nt * 16 + l15;
                #pragma unroll
                for (int mt = 0; mt < 4; ++mt)
                    #pragma unroll
                    for (int r = 0; r < 4; ++r) {
                        int e = mt * 16 + lhi * 4 + r;
                        Y2[(eb + e) * 1216 + 320 + jj] = (short)f2b(acc[g][mt][nt][r]);
                    }
            }
        }
    }
    conv_phase<2>(Zin + eb * 1216 + 832, 1216, 384, 384, V2, s_x, t, acc);
    #pragma unroll
    for (int g = 0; g < 2; ++g) {
        int grp = w + g * 8;
        if (grp < 12) {
            #pragma unroll
            for (int nt = 0; nt < 2; ++nt) {
                int jj = grp * 32 + nt * 16 + l15;
                #pragma unroll
                for (int mt = 0; mt < 4; ++mt)
                    #pragma unroll
                    for (int r = 0; r < 4; ++r) {
                        int e = mt * 16 + lhi * 4 + r;
                        Y2[(eb + e) * 1216 + 832 + jj] = (short)f2b(acc[g][mt][nt][r]);
                    }
            }
        }
    }
}

// ---------------- wigner_inv (fp32) + envelope + atomic scatter ----------------
__global__ void k_inv(const short* __restrict__ Y2, const float* __restrict__ winv,
                      const float* __restrict__ env, const int* __restrict__ rcv,
                      float* __restrict__ out, long e0, long nchunk, long Etot)
{
    __shared__ __align__(16) short s_y[16 * 1216];
    __shared__ float s_wv[16 * 475];
    const int t = threadIdx.x;
    const long eb = (long)blockIdx.x * 16;

    for (int p = t; p < 16 * 152; p += 256) {
        int e = p / 152, q = p - e * 152;
        *(uint4*)((char*)s_y + e * 2432 + q * 16) = *(const uint4*)(Y2 + (eb + e) * 1216 + q * 8);
    }
    for (int p = t; p < 16 * 475; p += 256) {
        int e = p / 475, q = p - e * 475;
        long ge = e0 + eb + e;
        s_wv[p] = (eb + e < nchunk && ge < Etot) ? winv[ge * 475 + q] : 0.f;
    }
    __syncthreads();

    for (int e = 0; e < 16; ++e) {
        long el = eb + e;
        if (el >= nchunk) break;
        long ge = e0 + el;
        float ev = env[ge];
        float* ob = out + (long)rcv[ge] * 1600;
        for (int f = t; f < 1600; f += 256) {
            int r = f >> 6, c = f & 63;
            float a = 0.f;
            #pragma unroll
            for (int k = 0; k < 19; ++k)
                a = fmaf(s_wv[e * 475 + r * 19 + k],
                         b2f((unsigned short)s_y[e * 1216 + k * 64 + c]), a);
            atomicAdd(ob + f, a * ev);
        }
    }
}

extern "C" void kernel_launch(void* const* d_in, const int* in_sizes, int n_in,
                              void* d_out, int out_size, void* d_ws, size_t ws_size,
                              hipStream_t stream)
{
    const float* nf   = (const float*)d_in[0];
    const float* ee   = (const float*)d_in[1];
    const float* wig  = (const float*)d_in[2];
    const float* winv = (const float*)d_in[3];
    const float* env  = (const float*)d_in[4];
    const float* rw1  = (const float*)d_in[5];
    const float* rb1  = (const float*)d_in[6];
    const float* rw2  = (const float*)d_in[7];
    const float* rb2  = (const float*)d_in[8];
    const float* w1m0 = (const float*)d_in[9];
    const float* b1m0 = (const float*)d_in[10];
    const float* w1r1 = (const float*)d_in[11];
    const float* w1i1 = (const float*)d_in[12];
    const float* w1r2 = (const float*)d_in[13];
    const float* w1i2 = (const float*)d_in[14];
    const float* w2m0 = (const float*)d_in[15];
    const float* b2m0 = (const float*)d_in[16];
    const float* w2r1 = (const float*)d_in[17];
    const float* w2i1 = (const float*)d_in[18];
    const float* w2r2 = (const float*)d_in[19];
    const float* w2i2 = (const float*)d_in[20];
    const int*   snd  = (const int*)d_in[21];
    const int*   rcv  = (const int*)d_in[22];
    float* out = (float*)d_out;
    short* Wb  = (short*)d_ws;

    const long E = in_sizes[21];

    hipMemsetAsync(d_out, 0, (size_t)out_size * sizeof(float), stream);
    k_prep<<<(int)((W_TOTAL + 511) / 512), 512, 0, stream>>>(
        w1m0, w1r1, w1i1, w1r2, w1i2, w2m0, w2r1, w2i1, w2r2, w2i2, rw2, Wb);

    // chunk edges so bf16 intermediates (12800 B/edge) + weights fit ws
    const size_t wbytes = (size_t)W_TOTAL * 2;
    long cap = 64;
    if (ws_size > wbytes) cap = (long)((ws_size - wbytes) / 12800);
    long chunk = (cap / 64) * 64;
    if (chunk < 64) chunk = 64;
    long Epad = ((E + 63) / 64) * 64;
    if (chunk > Epad) chunk = Epad;

    short* Xc   = Wb + W_TOTAL;
    short* radc = Xc + chunk * 2432;
    short* Zc   = radc + chunk * 1536;
    short* Y2c  = Zc + chunk * 1216;

    for (long base = 0; base < E; base += chunk) {
        long n = E - base; if (n > chunk) n = chunk;
        int nb = (int)((n + 63) / 64);
        k_rad  <<<nb * 2, 512, 0, stream>>>(ee, rw1, rb1, rb2, Wb + OFF_RW2T, radc, base, E);
        k_rot  <<<nb * 8, 256, 0, stream>>>(nf, wig, radc, snd, rcv, Xc, base, n, E);
        k_conv1<<<nb,     512, 0, stream>>>(Xc, Wb + OFF_W1T, Wb + OFF_W1C1, Wb + OFF_W1C2, b1m0, Zc);
        k_conv2<<<nb,     512, 0, stream>>>(Zc, Wb + OFF_V0T, Wb + OFF_V1C, Wb + OFF_V2C, b2m0, Y2c);
        k_inv  <<<nb * 4, 256, 0, stream>>>(Y2c, winv, env, rcv, out, base, n, E);
    }
    (void)n_in;
}

// Round 3
// 1636.597 us; speedup vs baseline: 3.3862x; 1.2581x over previous
//
#include <hip/hip_runtime.h>

// SO(2)-equivariant edge conv — bf16 MFMA pipeline, round 3.
// X per edge (2432 bf16): m0 rows0-4 [0,640) | m1 re+im rows5-12 [640,1664) | m2 [1664,2432)
// Z/Y2 per edge (1216 bf16): m0 [0,320) | m1 [320,832) | m2 [832,1216)
// Weights prepped transposed [N][K] bf16; complex convs combined: W=[[wr,wi],[-wi,wr]].
// ws aliasing: Y2 overwrites X; Z overwrites rad. CSR (hist/scan/scatter) kills atomics.

typedef __attribute__((ext_vector_type(8))) short bf16x8;
typedef __attribute__((ext_vector_type(4))) float f32x4;

__device__ __forceinline__ unsigned short f2b(float f) {
    unsigned u = __float_as_uint(f);
    unsigned r = (u + 0x7FFFu + ((u >> 16) & 1u)) >> 16;
    return (unsigned short)r;
}
__device__ __forceinline__ float b2f(unsigned short h) {
    return __uint_as_float(((unsigned)h) << 16);
}
__device__ __forceinline__ float sigm_(float x){ return 1.0f/(1.0f+__expf(-x)); }
__device__ __forceinline__ float silu_(float x){ return x/(1.0f+__expf(-x)); }

// weight region offsets (bf16 elems) in ws
#define OFF_W1T   0L
#define OFF_W1C1  368640L
#define OFF_W1C2  892928L
#define OFF_V0T   1187840L
#define OFF_V1C   1290240L
#define OFF_V2C   1552384L
#define OFF_RW2T  1699840L
#define W_TOTAL   1798144L
#define NNODES    2500

// ---------------- weight prep: f32 -> bf16, transpose to [N][K], fold complex ----
__global__ void k_prep(const float* __restrict__ w1m0, const float* __restrict__ w1r1,
                       const float* __restrict__ w1i1, const float* __restrict__ w1r2,
                       const float* __restrict__ w1i2, const float* __restrict__ w2m0,
                       const float* __restrict__ w2r1, const float* __restrict__ w2i1,
                       const float* __restrict__ w2r2, const float* __restrict__ w2i2,
                       const float* __restrict__ rw2, short* __restrict__ W)
{
    long i = (long)blockIdx.x * blockDim.x + threadIdx.x;
    if (i >= W_TOTAL) return;
    float v;
    if (i < OFF_W1C1) {                    // W1T [576][640]
        long n = i / 640, k = i - n * 640;
        v = w1m0[k * 576 + n];
    } else if (i < OFF_W1C2) {             // W1c1 [512][1024]
        long j = i - OFF_W1C1; int n = (int)(j >> 10), k = (int)(j & 1023);
        v = (n < 256) ? ((k < 512) ? w1r1[k*256 + n] : -w1i1[(k-512)*256 + n])
                      : ((k < 512) ? w1i1[k*256 + (n-256)] : w1r1[(k-512)*256 + (n-256)]);
    } else if (i < OFF_V0T) {              // W1c2 [384][768]
        long j = i - OFF_W1C2; int n = (int)(j / 768), k = (int)(j - (long)n * 768);
        v = (n < 192) ? ((k < 384) ? w1r2[k*192 + n] : -w1i2[(k-384)*192 + n])
                      : ((k < 384) ? w1i2[k*192 + (n-192)] : w1r2[(k-384)*192 + (n-192)]);
    } else if (i < OFF_V1C) {              // V0T [320][320]
        long j = i - OFF_V0T; int n = (int)(j / 320), k = (int)(j - (long)n * 320);
        v = w2m0[k * 320 + n];
    } else if (i < OFF_V2C) {              // V1c [512][512]
        long j = i - OFF_V1C; int n = (int)(j >> 9), k = (int)(j & 511);
        v = (n < 256) ? ((k < 256) ? w2r1[k*256 + n] : -w2i1[(k-256)*256 + n])
                      : ((k < 256) ? w2i1[k*256 + (n-256)] : w2r1[(k-256)*256 + (n-256)]);
    } else if (i < OFF_RW2T) {             // V2c [384][384]
        long j = i - OFF_V2C; int n = (int)(j / 384), k = (int)(j - (long)n * 384);
        v = (n < 192) ? ((k < 192) ? w2r2[k*192 + n] : -w2i2[(k-192)*192 + n])
                      : ((k < 192) ? w2i2[k*192 + (n-192)] : w2r2[(k-192)*192 + (n-192)]);
    } else {                               // RW2T [1536][64]
        long j = i - OFF_RW2T; int n = (int)(j >> 6), d = (int)(j & 63);
        v = rw2[d * 1536 + n];
    }
    W[i] = (short)f2b(v);
}

// ---------------- CSR build: histogram, scan, scatter ----------------
__global__ void k_hist(const int* __restrict__ rcv, int* __restrict__ cnt, long e0, long n)
{
    long e = (long)blockIdx.x * 256 + threadIdx.x;
    if (e < n) atomicAdd(&cnt[rcv[e0 + e]], 1);
}

__global__ __launch_bounds__(256)
void k_scan(const int* __restrict__ cnt, int* __restrict__ off, int* __restrict__ nxt)
{
    __shared__ int part[256];
    const int t = threadIdx.x;
    const int base = t * 10;
    int loc[10]; int s = 0;
    #pragma unroll
    for (int j = 0; j < 10; ++j) {
        int idx = base + j;
        int v = (idx < NNODES) ? cnt[idx] : 0;
        loc[j] = s; s += v;
    }
    part[t] = s;
    __syncthreads();
    for (int d = 1; d < 256; d <<= 1) {
        int v = part[t];
        int u = (t >= d) ? part[t - d] : 0;
        __syncthreads();
        part[t] = v + u;
        __syncthreads();
    }
    int excl = (t == 0) ? 0 : part[t - 1];
    #pragma unroll
    for (int j = 0; j < 10; ++j) {
        int idx = base + j;
        if (idx < NNODES) { int o = excl + loc[j]; off[idx] = o; nxt[idx] = o; }
    }
}

__global__ void k_scat(const int* __restrict__ rcv, int* __restrict__ nxt,
                       int* __restrict__ perm, long e0, long n)
{
    long e = (long)blockIdx.x * 256 + threadIdx.x;
    if (e < n) {
        int p = atomicAdd(&nxt[rcv[e0 + e]], 1);
        perm[p] = (int)e;
    }
}

// ---------------- radial MLP: h = silu(ee@rw1+rb1) [VALU]; rad = h@rw2+rb2 [MFMA] ----
__global__ __launch_bounds__(512)
void k_rad(const float* __restrict__ ee, const float* __restrict__ rw1,
           const float* __restrict__ rb1, const float* __restrict__ rb2,
           const short* __restrict__ RW2T, short* __restrict__ rad,
           long e0, long Etot)
{
    __shared__ __align__(16) short s_h[32 * 64];
    const int t = threadIdx.x, w = t >> 6, l = t & 63, l15 = l & 15, lhi = l >> 4;
    const long eb = (long)blockIdx.x * 32;

    #pragma unroll
    for (int j = 0; j < 4; ++j) {
        int i = t + j * 512;
        int e = i >> 6, d = i & 63;
        long ge = e0 + eb + e;
        float a = rb1[d];
        if (ge < Etot) {
            const float* ep = ee + ge * 128;
            #pragma unroll 16
            for (int dd = 0; dd < 128; ++dd) a = fmaf(ep[dd], rw1[dd * 64 + d], a);
            a = silu_(a);
        } else a = 0.f;
        *(short*)((char*)s_h + e * 128 + ((d * 2) ^ ((e & 7) << 4))) = (short)f2b(a);
    }
    __syncthreads();

    f32x4 acc[6][2][2];
    #pragma unroll
    for (int g = 0; g < 6; ++g)
        #pragma unroll
        for (int mt = 0; mt < 2; ++mt)
            #pragma unroll
            for (int nt = 0; nt < 2; ++nt)
                acc[g][mt][nt] = (f32x4){0.f, 0.f, 0.f, 0.f};

    #pragma unroll
    for (int ks = 0; ks < 2; ++ks) {
        bf16x8 af[2];
        #pragma unroll
        for (int mt = 0; mt < 2; ++mt)
            af[mt] = *(const bf16x8*)((const char*)s_h + (mt * 16 + l15) * 128 +
                                      (((ks << 6) + (lhi << 4)) ^ ((l & 7) << 4)));
        #pragma unroll
        for (int g = 0; g < 6; ++g) {
            int grp = w + g * 8;
            #pragma unroll
            for (int nt = 0; nt < 2; ++nt) {
                int col = grp * 32 + nt * 16 + l15;
                bf16x8 bf = *(const bf16x8*)(RW2T + (long)col * 64 + (ks << 5) + (lhi << 3));
                #pragma unroll
                for (int mt = 0; mt < 2; ++mt)
                    acc[g][mt][nt] = __builtin_amdgcn_mfma_f32_16x16x32_bf16(af[mt], bf, acc[g][mt][nt], 0, 0, 0);
            }
        }
    }
    #pragma unroll
    for (int g = 0; g < 6; ++g)
        #pragma unroll
        for (int nt = 0; nt < 2; ++nt) {
            int col = (w + g * 8) * 32 + nt * 16 + l15;
            float bias = rb2[col];
            #pragma unroll
            for (int mt = 0; mt < 2; ++mt)
                #pragma unroll
                for (int r = 0; r < 4; ++r) {
                    int e = mt * 16 + lhi * 4 + r;
                    rad[(eb + e) * 1536 + col] = (short)f2b(acc[g][mt][nt][r] + bias);
                }
        }
}

// ---------------- gather + wigner rotate (fp32) * rad -> X bf16 ----------------
__global__ void k_rot(const float* __restrict__ nf, const float* __restrict__ wig,
                      const short* __restrict__ rad,
                      const int* __restrict__ snd, const int* __restrict__ rcv,
                      short* __restrict__ X, long e0, long nchunk, long Etot)
{
    const int t = threadIdx.x;
    const long eb = (long)blockIdx.x * 8;
    #pragma unroll
    for (int j = 0; j < 4; ++j) {
        int i = t + j * 256;
        int e = i >> 7, c = i & 127;
        long el = eb + e;
        short* xrow = X + el * 2432;
        if (el >= nchunk) {
            #pragma unroll
            for (int r = 0; r < 19; ++r) xrow[r * 128 + c] = 0;
            continue;
        }
        long ge = e0 + el;
        int node = (c < 64) ? snd[ge] : rcv[ge];
        const float* npt = nf + (long)node * 1600 + (c & 63);
        float m[25];
        #pragma unroll
        for (int k = 0; k < 25; ++k) m[k] = npt[k * 64];
        const float* wp = wig + ge * 475;
        const short* rp = rad + el * 1536;
        #pragma unroll
        for (int r = 0; r < 19; ++r) {
            float a = 0.f;
            #pragma unroll
            for (int k = 0; k < 25; ++k) a = fmaf(wp[r * 25 + k], m[k], a);
            int rr = (r < 9) ? r : ((r < 16) ? r - 4 : r - 7);
            a *= b2f((unsigned short)rp[rr * 128 + c]);
            xrow[r * 128 + c] = (short)f2b(a);
        }
    }
}

// ---------------- templated MFMA GEMM phase (BK=128, ks fully unrolled) ----------
// A: [64 edges][Km] bf16 at Xp (+e*RS), staged via regs to XOR-swizzled LDS.
// B: W [Nm][Km] bf16 transposed, 16B frags from L2 (shared across blocks).
template<int Km, int Nm, int NACC>
__device__ __forceinline__ void conv_phase(
    const short* __restrict__ Xp, const long RS,
    const short* __restrict__ W, short* __restrict__ s_x, const int t,
    f32x4 (&acc)[NACC][4][2])
{
    const int w = t >> 6, l = t & 63, l15 = l & 15, lhi = l >> 4;
    const int swz = (l & 7) << 4;
    constexpr int NCHF = Km / 128;
    constexpr int TAIL = Km % 128;          // 0 or 64

    #pragma unroll
    for (int g = 0; g < NACC; ++g)
        #pragma unroll
        for (int mt = 0; mt < 4; ++mt)
            #pragma unroll
            for (int nt = 0; nt < 2; ++nt)
                acc[g][mt][nt] = (f32x4){0.f, 0.f, 0.f, 0.f};

    const int e_a = t >> 4,          k8_a = t & 15;          // j=0 (p = t)
    const int e_b = (t + 512) >> 4,  k8_b = (t + 512) & 15;  // j=1
    const int e_t = t >> 3,          k8_t = t & 7;           // tail pattern (t<512)

    uint4 ra0 = *(const uint4*)(Xp + (long)e_a * RS + (k8_a << 3));
    uint4 ra1 = *(const uint4*)(Xp + (long)e_b * RS + (k8_b << 3));

    auto mma_ks = [&](int kc0, int ks) {
        bf16x8 af[4];
        #pragma unroll
        for (int mt = 0; mt < 4; ++mt)
            af[mt] = *(const bf16x8*)((const char*)s_x + (mt * 16 + l15) * 256 +
                                      (((ks << 6) + (lhi << 4)) ^ swz));
        #pragma unroll
        for (int g = 0; g < NACC; ++g) {
            const int grp = w + (g << 3);
            if ((grp << 5) < Nm) {
                #pragma unroll
                for (int nt = 0; nt < 2; ++nt) {
                    const int col = (grp << 5) + (nt << 4) + l15;
                    bf16x8 bf = *(const bf16x8*)(W + (long)col * Km + kc0 + (ks << 5) + (lhi << 3));
                    #pragma unroll
                    for (int mt = 0; mt < 4; ++mt)
                        acc[g][mt][nt] = __builtin_amdgcn_mfma_f32_16x16x32_bf16(af[mt], bf, acc[g][mt][nt], 0, 0, 0);
                }
            }
        }
    };

    for (int ch = 0; ch < NCHF; ++ch) {
        __syncthreads();
        *(uint4*)((char*)s_x + e_a * 256 + ((k8_a << 4) ^ ((e_a & 7) << 4))) = ra0;
        *(uint4*)((char*)s_x + e_b * 256 + ((k8_b << 4) ^ ((e_b & 7) << 4))) = ra1;
        const int kc1 = (ch + 1) << 7;
        if (ch + 1 < NCHF) {
            ra0 = *(const uint4*)(Xp + (long)e_a * RS + kc1 + (k8_a << 3));
            ra1 = *(const uint4*)(Xp + (long)e_b * RS + kc1 + (k8_b << 3));
        } else if constexpr (TAIL != 0) {
            if (t < 512) ra0 = *(const uint4*)(Xp + (long)e_t * RS + kc1 + (k8_t << 3));
        }
        __syncthreads();
        const int kc0 = ch << 7;
        #pragma unroll
        for (int ks = 0; ks < 4; ++ks) mma_ks(kc0, ks);
    }
    if constexpr (TAIL != 0) {
        __syncthreads();
        if (t < 512)
            *(uint4*)((char*)s_x + e_t * 256 + ((k8_t << 4) ^ ((e_t & 7) << 4))) = ra0;
        __syncthreads();
        constexpr int kc0 = NCHF << 7;
        #pragma unroll
        for (int ks = 0; ks < TAIL / 32; ++ks) mma_ks(kc0, ks);
    }
}

// ---------------- conv1 + fused gate -> Z bf16 [E,1216] ----------------
__global__ __launch_bounds__(512)
void k_conv1(const short* __restrict__ X, const short* __restrict__ W0,
             const short* __restrict__ W1, const short* __restrict__ W2,
             const float* __restrict__ b1m0, short* __restrict__ Z)
{
    __shared__ __align__(16) short s_x[64 * 128];
    __shared__ __align__(16) short s_g[64 * 256];
    const int t = threadIdx.x, w = t >> 6, l = t & 63, l15 = l & 15, lhi = l >> 4;
    const long eb = (long)blockIdx.x * 64;

    // ===== m0: K=640 -> N=576 (320 out + 256 gating) =====
    {
        f32x4 acc[3][4][2];
        conv_phase<640, 576, 3>(X + eb * 2432, 2432, W0, s_x, t, acc);
        #pragma unroll
        for (int g = 0; g < 3; ++g) {
            int grp = w + g * 8;
            if (grp < 18) {
                #pragma unroll
                for (int nt = 0; nt < 2; ++nt) {
                    int jj = grp * 32 + nt * 16 + l15;
                    if (jj >= 320) {
                        float bias = b1m0[jj];
                        #pragma unroll
                        for (int mt = 0; mt < 4; ++mt)
                            #pragma unroll
                            for (int r = 0; r < 4; ++r) {
                                int e = mt * 16 + lhi * 4 + r;
                                s_g[e * 256 + (jj - 320)] = (short)f2b(sigm_(acc[g][mt][nt][r] + bias));
                            }
                    }
                }
            }
        }
        __syncthreads();
        #pragma unroll
        for (int g = 0; g < 3; ++g) {
            int grp = w + g * 8;
            if (grp < 10) {
                #pragma unroll
                for (int nt = 0; nt < 2; ++nt) {
                    int jj = grp * 32 + nt * 16 + l15;
                    float bias = b1m0[jj];
                    int r0 = jj >> 6;
                    #pragma unroll
                    for (int mt = 0; mt < 4; ++mt)
                        #pragma unroll
                        for (int r = 0; r < 4; ++r) {
                            int e = mt * 16 + lhi * 4 + r;
                            float v = acc[g][mt][nt][r] + bias;
                            float zv = (r0 == 0) ? silu_(v)
                                     : v * b2f((unsigned short)s_g[e * 256 + (r0 - 1) * 64 + (jj & 63)]);
                            Z[(eb + e) * 1216 + jj] = (short)f2b(zv);
                        }
                }
            }
        }
    }

    // ===== m1: K=1024 -> N=512, gate idx = j & 255 =====
    {
        f32x4 acc[2][4][2];
        conv_phase<1024, 512, 2>(X + eb * 2432 + 640, 2432, W1, s_x, t, acc);
        #pragma unroll
        for (int g = 0; g < 2; ++g) {
            int grp = w + g * 8;
            #pragma unroll
            for (int nt = 0; nt < 2; ++nt) {
                int jj = grp * 32 + nt * 16 + l15;
                #pragma unroll
                for (int mt = 0; mt < 4; ++mt)
                    #pragma unroll
                    for (int r = 0; r < 4; ++r) {
                        int e = mt * 16 + lhi * 4 + r;
                        float gt = b2f((unsigned short)s_g[e * 256 + (jj & 255)]);
                        Z[(eb + e) * 1216 + 320 + jj] = (short)f2b(acc[g][mt][nt][r] * gt);
                    }
            }
        }
    }

    // ===== m2: K=768 -> N=384, gate idx = 64 + (j mod 192) =====
    {
        f32x4 acc[2][4][2];
        conv_phase<768, 384, 2>(X + eb * 2432 + 1664, 2432, W2, s_x, t, acc);
        #pragma unroll
        for (int g = 0; g < 2; ++g) {
            int grp = w + g * 8;
            if (grp < 12) {
                #pragma unroll
                for (int nt = 0; nt < 2; ++nt) {
                    int jj = grp * 32 + nt * 16 + l15;
                    int jm = (jj >= 192) ? jj - 192 : jj;
                    #pragma unroll
                    for (int mt = 0; mt < 4; ++mt)
                        #pragma unroll
                        for (int r = 0; r < 4; ++r) {
                            int e = mt * 16 + lhi * 4 + r;
                            float gt = b2f((unsigned short)s_g[e * 256 + 64 + jm]);
                            Z[(eb + e) * 1216 + 832 + jj] = (short)f2b(acc[g][mt][nt][r] * gt);
                        }
                }
            }
        }
    }
}

// ---------------- conv2 -> Y2 bf16 [E,1216] ----------------
__global__ __launch_bounds__(512)
void k_conv2(const short* __restrict__ Zin, const short* __restrict__ V0,
             const short* __restrict__ V1, const short* __restrict__ V2,
             const float* __restrict__ b2m0, short* __restrict__ Y2)
{
    __shared__ __align__(16) short s_x[64 * 128];
    const int t = threadIdx.x, w = t >> 6, l = t & 63, l15 = l & 15, lhi = l >> 4;
    const long eb = (long)blockIdx.x * 64;

    {
        f32x4 acc[2][4][2];
        conv_phase<320, 320, 2>(Zin + eb * 1216, 1216, V0, s_x, t, acc);
        #pragma unroll
        for (int g = 0; g < 2; ++g) {
            int grp = w + g * 8;
            if (grp < 10) {
                #pragma unroll
                for (int nt = 0; nt < 2; ++nt) {
                    int jj = grp * 32 + nt * 16 + l15;
                    float bias = b2m0[jj];
                    #pragma unroll
                    for (int mt = 0; mt < 4; ++mt)
                        #pragma unroll
                        for (int r = 0; r < 4; ++r) {
                            int e = mt * 16 + lhi * 4 + r;
                            Y2[(eb + e) * 1216 + jj] = (short)f2b(acc[g][mt][nt][r] + bias);
                        }
                }
            }
        }
    }
    {
        f32x4 acc[2][4][2];
        conv_phase<512, 512, 2>(Zin + eb * 1216 + 320, 1216, V1, s_x, t, acc);
        #pragma unroll
        for (int g = 0; g < 2; ++g) {
            int grp = w + g * 8;
            #pragma unroll
            for (int nt = 0; nt < 2; ++nt) {
                int jj = grp * 32 + nt * 16 + l15;
                #pragma unroll
                for (int mt = 0; mt < 4; ++mt)
                    #pragma unroll
                    for (int r = 0; r < 4; ++r) {
                        int e = mt * 16 + lhi * 4 + r;
                        Y2[(eb + e) * 1216 + 320 + jj] = (short)f2b(acc[g][mt][nt][r]);
                    }
            }
        }
    }
    {
        f32x4 acc[2][4][2];
        conv_phase<384, 384, 2>(Zin + eb * 1216 + 832, 1216, V2, s_x, t, acc);
        #pragma unroll
        for (int g = 0; g < 2; ++g) {
            int grp = w + g * 8;
            if (grp < 12) {
                #pragma unroll
                for (int nt = 0; nt < 2; ++nt) {
                    int jj = grp * 32 + nt * 16 + l15;
                    #pragma unroll
                    for (int mt = 0; mt < 4; ++mt)
                        #pragma unroll
                        for (int r = 0; r < 4; ++r) {
                            int e = mt * 16 + lhi * 4 + r;
                            Y2[(eb + e) * 1216 + 832 + jj] = (short)f2b(acc[g][mt][nt][r]);
                        }
                }
            }
        }
    }
}

// ---------------- node-major: wigner_inv + envelope + segment sum (no atomics) ----
__global__ __launch_bounds__(256)
void k_invn(const short* __restrict__ Y2, const float* __restrict__ winv,
            const float* __restrict__ env, const int* __restrict__ cnt,
            const int* __restrict__ off, const int* __restrict__ perm,
            float* __restrict__ out, long e0)
{
    __shared__ __align__(16) short s_y[2][1216];
    __shared__ float s_wv[2][476];
    const int t = threadIdx.x;
    const int n = blockIdx.x;
    const int deg = cnt[n], start = off[n];

    float acc[7];
    #pragma unroll
    for (int j = 0; j < 7; ++j) acc[j] = 0.f;

    auto stage = [&](int i, int b) {
        int el = perm[start + i];
        long ge = e0 + el;
        if (t < 152) ((uint4*)s_y[b])[t] = *(const uint4*)(Y2 + (long)el * 1216 + t * 8);
        for (int p = t; p < 475; p += 256) s_wv[b][p] = winv[ge * 475 + p];
        if (t == 0) s_wv[b][475] = env[ge];
    };

    if (deg > 0) stage(0, 0);
    for (int i = 0; i < deg; ++i) {
        __syncthreads();
        if (i + 1 < deg) stage(i + 1, (i + 1) & 1);
        const short* sy = s_y[i & 1];
        const float* sw = s_wv[i & 1];
        float ev = sw[475];
        #pragma unroll
        for (int j = 0; j < 7; ++j) {
            int f = t + j * 256;
            if (f < 1600) {
                int r = f >> 6, c = f & 63;
                float a = 0.f;
                #pragma unroll
                for (int k = 0; k < 19; ++k)
                    a = fmaf(sw[r * 19 + k], b2f((unsigned short)sy[k * 64 + c]), a);
                acc[j] = fmaf(a, ev, acc[j]);
            }
        }
    }
    #pragma unroll
    for (int j = 0; j < 7; ++j) {
        int f = t + j * 256;
        if (f < 1600) out[(long)n * 1600 + f] += acc[j];
    }
}

extern "C" void kernel_launch(void* const* d_in, const int* in_sizes, int n_in,
                              void* d_out, int out_size, void* d_ws, size_t ws_size,
                              hipStream_t stream)
{
    const float* nf   = (const float*)d_in[0];
    const float* ee   = (const float*)d_in[1];
    const float* wig  = (const float*)d_in[2];
    const float* winv = (const float*)d_in[3];
    const float* env  = (const float*)d_in[4];
    const float* rw1  = (const float*)d_in[5];
    const float* rb1  = (const float*)d_in[6];
    const float* rw2  = (const float*)d_in[7];
    const float* rb2  = (const float*)d_in[8];
    const float* w1m0 = (const float*)d_in[9];
    const float* b1m0 = (const float*)d_in[10];
    const float* w1r1 = (const float*)d_in[11];
    const float* w1i1 = (const float*)d_in[12];
    const float* w1r2 = (const float*)d_in[13];
    const float* w1i2 = (const float*)d_in[14];
    const float* w2m0 = (const float*)d_in[15];
    const float* b2m0 = (const float*)d_in[16];
    const float* w2r1 = (const float*)d_in[17];
    const float* w2i1 = (const float*)d_in[18];
    const float* w2r2 = (const float*)d_in[19];
    const float* w2i2 = (const float*)d_in[20];
    const int*   snd  = (const int*)d_in[21];
    const int*   rcv  = (const int*)d_in[22];
    float* out = (float*)d_out;

    const long E = in_sizes[21];

    short* Wb = (short*)d_ws;
    int* cnt  = (int*)(Wb + W_TOTAL);
    int* off  = cnt + 2512;
    int* nxt  = off + 2512;
    int* perm = nxt + 2512;

    // per-edge ws: perm 4B + X 4864B (reused by Y2) + rad 3072B (reused by Z)
    const size_t fixed = (size_t)W_TOTAL * 2 + 3 * 2512 * 4;
    long cap = (ws_size > fixed) ? (long)((ws_size - fixed) / 7940) : 64;
    long chunk = (cap / 64) * 64;
    if (chunk < 64) chunk = 64;
    long Epad = ((E + 63) / 64) * 64;
    if (chunk > Epad) chunk = Epad;

    short* Xc = (short*)(perm + chunk);     // chunk*2432, also Y2
    short* Rc = Xc + chunk * 2432;          // chunk*1536, also Z

    hipMemsetAsync(d_out, 0, (size_t)out_size * sizeof(float), stream);
    k_prep<<<(int)((W_TOTAL + 511) / 512), 512, 0, stream>>>(
        w1m0, w1r1, w1i1, w1r2, w1i2, w2m0, w2r1, w2i1, w2r2, w2i2, rw2, Wb);

    for (long base = 0; base < E; base += chunk) {
        long n = E - base; if (n > chunk) n = chunk;
        int nb  = (int)((n + 63) / 64);
        int nbe = (int)((n + 255) / 256);

        hipMemsetAsync(cnt, 0, NNODES * sizeof(int), stream);
        k_hist<<<nbe, 256, 0, stream>>>(rcv, cnt, base, n);
        k_scan<<<1, 256, 0, stream>>>(cnt, off, nxt);
        k_scat<<<nbe, 256, 0, stream>>>(rcv, nxt, perm, base, n);

        k_rad  <<<nb * 2, 512, 0, stream>>>(ee, rw1, rb1, rb2, Wb + OFF_RW2T, Rc, base, E);
        k_rot  <<<nb * 8, 256, 0, stream>>>(nf, wig, Rc, snd, rcv, Xc, base, n, E);
        k_conv1<<<nb,     512, 0, stream>>>(Xc, Wb + OFF_W1T, Wb + OFF_W1C1, Wb + OFF_W1C2, b1m0, Rc);
        k_conv2<<<nb,     512, 0, stream>>>(Rc, Wb + OFF_V0T, Wb + OFF_V1C, Wb + OFF_V2C, b2m0, Xc);
        k_invn <<<NNODES, 256, 0, stream>>>(Xc, winv, env, cnt, off, perm, out, base);
    }
    (void)n_in;
}

// Round 4
// 1462.319 us; speedup vs baseline: 3.7898x; 1.1192x over previous
//
#include <hip/hip_runtime.h>

// SO(2)-equivariant edge conv — bf16 MFMA pipeline, round 4.
// X per edge (2432 bf16): m0 rows0-4 [0,640) | m1 re+im rows5-12 [640,1664) | m2 [1664,2432)
// Z/Y2 per edge (1216 bf16): m0 [0,320) | m1 [320,832) | m2 [832,1216)
// Weights prepped transposed [N][K] bf16; complex convs combined: W=[[wr,wi],[-wi,wr]].
// NEW: wigner rotation via MFMA (one wave per edge), nfT = transposed node feats,
// Wg (padded bf16 wigner) aliased into X rows (read-before-overwrite within block).

typedef __attribute__((ext_vector_type(8))) short bf16x8;
typedef __attribute__((ext_vector_type(4))) float f32x4;

__device__ __forceinline__ unsigned short f2b(float f) {
    unsigned u = __float_as_uint(f);
    unsigned r = (u + 0x7FFFu + ((u >> 16) & 1u)) >> 16;
    return (unsigned short)r;
}
__device__ __forceinline__ float b2f(unsigned short h) {
    return __uint_as_float(((unsigned)h) << 16);
}
__device__ __forceinline__ float sigm_(float x){ return 1.0f/(1.0f+__expf(-x)); }
__device__ __forceinline__ float silu_(float x){ return x/(1.0f+__expf(-x)); }

// weight region offsets (bf16 elems) in ws
#define OFF_W1T   0L
#define OFF_W1C1  368640L
#define OFF_W1C2  892928L
#define OFF_V0T   1187840L
#define OFF_V1C   1290240L
#define OFF_V2C   1552384L
#define OFF_RW2T  1699840L
#define W_TOTAL   1798144L
#define NNODES    2500
#define NFT_ELEMS (2500L * 2048L)

// ---------------- weight prep: f32 -> bf16, transpose to [N][K], fold complex ----
__global__ void k_prep(const float* __restrict__ w1m0, const float* __restrict__ w1r1,
                       const float* __restrict__ w1i1, const float* __restrict__ w1r2,
                       const float* __restrict__ w1i2, const float* __restrict__ w2m0,
                       const float* __restrict__ w2r1, const float* __restrict__ w2i1,
                       const float* __restrict__ w2r2, const float* __restrict__ w2i2,
                       const float* __restrict__ rw2, short* __restrict__ W)
{
    long i = (long)blockIdx.x * blockDim.x + threadIdx.x;
    if (i >= W_TOTAL) return;
    float v;
    if (i < OFF_W1C1) {                    // W1T [576][640]
        long n = i / 640, k = i - n * 640;
        v = w1m0[k * 576 + n];
    } else if (i < OFF_W1C2) {             // W1c1 [512][1024]
        long j = i - OFF_W1C1; int n = (int)(j >> 10), k = (int)(j & 1023);
        v = (n < 256) ? ((k < 512) ? w1r1[k*256 + n] : -w1i1[(k-512)*256 + n])
                      : ((k < 512) ? w1i1[k*256 + (n-256)] : w1r1[(k-512)*256 + (n-256)]);
    } else if (i < OFF_V0T) {              // W1c2 [384][768]
        long j = i - OFF_W1C2; int n = (int)(j / 768), k = (int)(j - (long)n * 768);
        v = (n < 192) ? ((k < 384) ? w1r2[k*192 + n] : -w1i2[(k-384)*192 + n])
                      : ((k < 384) ? w1i2[k*192 + (n-192)] : w1r2[(k-384)*192 + (n-192)]);
    } else if (i < OFF_V1C) {              // V0T [320][320]
        long j = i - OFF_V0T; int n = (int)(j / 320), k = (int)(j - (long)n * 320);
        v = w2m0[k * 320 + n];
    } else if (i < OFF_V2C) {              // V1c [512][512]
        long j = i - OFF_V1C; int n = (int)(j >> 9), k = (int)(j & 511);
        v = (n < 256) ? ((k < 256) ? w2r1[k*256 + n] : -w2i1[(k-256)*256 + n])
                      : ((k < 256) ? w2i1[k*256 + (n-256)] : w2r1[(k-256)*256 + (n-256)]);
    } else if (i < OFF_RW2T) {             // V2c [384][384]
        long j = i - OFF_V2C; int n = (int)(j / 384), k = (int)(j - (long)n * 384);
        v = (n < 192) ? ((k < 192) ? w2r2[k*192 + n] : -w2i2[(k-192)*192 + n])
                      : ((k < 192) ? w2i2[k*192 + (n-192)] : w2r2[(k-192)*192 + (n-192)]);
    } else {                               // RW2T [1536][64]
        long j = i - OFF_RW2T; int n = (int)(j >> 6), d = (int)(j & 63);
        v = rw2[d * 1536 + n];
    }
    W[i] = (short)f2b(v);
}

// ---------------- node-feature transpose: nfT[n][c][k<32] = nf[n][k][c] (bf16) ----
__global__ __launch_bounds__(256)
void k_nft(const float* __restrict__ nf, short* __restrict__ nfT)
{
    __shared__ float s_nf[25 * 65];
    const int t = threadIdx.x;
    const long nn = blockIdx.x;
    for (int p = t; p < 1600; p += 256) {
        int r = p >> 6, c = p & 63;
        s_nf[r * 65 + c] = nf[nn * 1600 + p];
    }
    __syncthreads();
    for (int i = t; i < 2048; i += 256) {
        int c = i >> 5, k = i & 31;
        float v = (k < 25) ? s_nf[k * 65 + c] : 0.f;
        nfT[nn * 2048 + i] = (short)f2b(v);
    }
}

// ---------------- wigner -> bf16 padded [19][32], aliased into X rows ----------
__global__ __launch_bounds__(256)
void k_wig(const float* __restrict__ wig, short* __restrict__ Xc, long e0, long n)
{
    const int t = threadIdx.x;
    const long eb = (long)blockIdx.x * 8;
    for (int el = 0; el < 8; ++el) {
        long e = eb + el;
        if (e >= n) break;
        const float* wp = wig + (e0 + e) * 475;
        short* dst = Xc + e * 2432;
        for (int p = t; p < 608; p += 256) {
            int r = p >> 5, k = p & 31;
            dst[p] = (short)f2b((k < 25) ? wp[r * 25 + k] : 0.f);
        }
    }
}

// ---------------- CSR build: histogram, scan, scatter ----------------
__global__ void k_hist(const int* __restrict__ rcv, int* __restrict__ cnt, long e0, long n)
{
    long e = (long)blockIdx.x * 256 + threadIdx.x;
    if (e < n) atomicAdd(&cnt[rcv[e0 + e]], 1);
}

__global__ __launch_bounds__(256)
void k_scan(const int* __restrict__ cnt, int* __restrict__ off, int* __restrict__ nxt)
{
    __shared__ int part[256];
    const int t = threadIdx.x;
    const int base = t * 10;
    int loc[10]; int s = 0;
    #pragma unroll
    for (int j = 0; j < 10; ++j) {
        int idx = base + j;
        int v = (idx < NNODES) ? cnt[idx] : 0;
        loc[j] = s; s += v;
    }
    part[t] = s;
    __syncthreads();
    for (int d = 1; d < 256; d <<= 1) {
        int v = part[t];
        int u = (t >= d) ? part[t - d] : 0;
        __syncthreads();
        part[t] = v + u;
        __syncthreads();
    }
    int excl = (t == 0) ? 0 : part[t - 1];
    #pragma unroll
    for (int j = 0; j < 10; ++j) {
        int idx = base + j;
        if (idx < NNODES) { int o = excl + loc[j]; off[idx] = o; nxt[idx] = o; }
    }
}

__global__ void k_scat(const int* __restrict__ rcv, int* __restrict__ nxt,
                       int* __restrict__ perm, long e0, long n)
{
    long e = (long)blockIdx.x * 256 + threadIdx.x;
    if (e < n) {
        int p = atomicAdd(&nxt[rcv[e0 + e]], 1);
        perm[p] = (int)e;
    }
}

// ---------------- radial MLP: h = silu(ee@rw1+rb1) [VALU]; rad = h@rw2+rb2 [MFMA] ----
__global__ __launch_bounds__(512)
void k_rad(const float* __restrict__ ee, const float* __restrict__ rw1,
           const float* __restrict__ rb1, const float* __restrict__ rb2,
           const short* __restrict__ RW2T, short* __restrict__ rad,
           long e0, long Etot)
{
    __shared__ __align__(16) short s_h[32 * 64];
    const int t = threadIdx.x, w = t >> 6, l = t & 63, l15 = l & 15, lhi = l >> 4;
    const long eb = (long)blockIdx.x * 32;

    #pragma unroll
    for (int j = 0; j < 4; ++j) {
        int i = t + j * 512;
        int e = i >> 6, d = i & 63;
        long ge = e0 + eb + e;
        float a = rb1[d];
        if (ge < Etot) {
            const float* ep = ee + ge * 128;
            #pragma unroll 16
            for (int dd = 0; dd < 128; ++dd) a = fmaf(ep[dd], rw1[dd * 64 + d], a);
            a = silu_(a);
        } else a = 0.f;
        *(short*)((char*)s_h + e * 128 + ((d * 2) ^ ((e & 7) << 4))) = (short)f2b(a);
    }
    __syncthreads();

    f32x4 acc[6][2][2];
    #pragma unroll
    for (int g = 0; g < 6; ++g)
        #pragma unroll
        for (int mt = 0; mt < 2; ++mt)
            #pragma unroll
            for (int nt = 0; nt < 2; ++nt)
                acc[g][mt][nt] = (f32x4){0.f, 0.f, 0.f, 0.f};

    #pragma unroll
    for (int ks = 0; ks < 2; ++ks) {
        bf16x8 af[2];
        #pragma unroll
        for (int mt = 0; mt < 2; ++mt)
            af[mt] = *(const bf16x8*)((const char*)s_h + (mt * 16 + l15) * 128 +
                                      (((ks << 6) + (lhi << 4)) ^ ((l & 7) << 4)));
        #pragma unroll
        for (int g = 0; g < 6; ++g) {
            int grp = w + g * 8;
            #pragma unroll
            for (int nt = 0; nt < 2; ++nt) {
                int col = grp * 32 + nt * 16 + l15;
                bf16x8 bf = *(const bf16x8*)(RW2T + (long)col * 64 + (ks << 5) + (lhi << 3));
                #pragma unroll
                for (int mt = 0; mt < 2; ++mt)
                    acc[g][mt][nt] = __builtin_amdgcn_mfma_f32_16x16x32_bf16(af[mt], bf, acc[g][mt][nt], 0, 0, 0);
            }
        }
    }
    #pragma unroll
    for (int g = 0; g < 6; ++g)
        #pragma unroll
        for (int nt = 0; nt < 2; ++nt) {
            int col = (w + g * 8) * 32 + nt * 16 + l15;
            float bias = rb2[col];
            #pragma unroll
            for (int mt = 0; mt < 2; ++mt)
                #pragma unroll
                for (int r = 0; r < 4; ++r) {
                    int e = mt * 16 + lhi * 4 + r;
                    rad[(eb + e) * 1536 + col] = (short)f2b(acc[g][mt][nt][r] + bias);
                }
        }
}

// ---------------- MFMA wigner rotate: X[19][128] = Wg[19][32] @ msgT, * rad ----
// One wave per edge. Wg aliased at X+el*2432 (read before overwrite, sync'd).
__global__ __launch_bounds__(256)
void k_rot2(const short* __restrict__ nfT, const short* __restrict__ rad,
            const int* __restrict__ snd, const int* __restrict__ rcv,
            short* __restrict__ X, long e0, long nchunk)
{
    __shared__ float s_rot[4][128 * 20];   // [edge][col*20 + row], row padded to 20
    const int t = threadIdx.x, w = t >> 6, l = t & 63, l15 = l & 15, lhi = l >> 4;
    const long eb = (long)blockIdx.x * 4;
    const long el = eb + w;

    if (el < nchunk) {
        long ge = e0 + el;
        int n0 = snd[ge], n1 = rcv[ge];
        const short* wg = X + el * 2432;
        bf16x8 a0 = *(const bf16x8*)(wg + l15 * 32 + lhi * 8);
        bf16x8 a1 = {0,0,0,0,0,0,0,0};
        if (l15 < 3) a1 = *(const bf16x8*)(wg + (16 + l15) * 32 + lhi * 8);

        f32x4 acc0[8], acc1[8];
        #pragma unroll
        for (int nt = 0; nt < 8; ++nt) {
            acc0[nt] = (f32x4){0.f, 0.f, 0.f, 0.f};
            acc1[nt] = (f32x4){0.f, 0.f, 0.f, 0.f};
        }
        #pragma unroll
        for (int nt = 0; nt < 8; ++nt) {
            int col = nt * 16 + l15;
            bf16x8 b = *(const bf16x8*)(nfT + (long)(col < 64 ? n0 : n1) * 2048 +
                                        (long)(col & 63) * 32 + (lhi << 3));
            acc0[nt] = __builtin_amdgcn_mfma_f32_16x16x32_bf16(a0, b, acc0[nt], 0, 0, 0);
            acc1[nt] = __builtin_amdgcn_mfma_f32_16x16x32_bf16(a1, b, acc1[nt], 0, 0, 0);
        }
        #pragma unroll
        for (int nt = 0; nt < 8; ++nt) {
            int col = nt * 16 + l15;
            *(f32x4*)&s_rot[w][col * 20 + lhi * 4] = acc0[nt];      // rows 0..15
            if (lhi == 0) *(f32x4*)&s_rot[w][col * 20 + 16] = acc1[nt]; // rows 16..19(pad)
        }
    }
    __syncthreads();

    #pragma unroll
    for (int e2 = 0; e2 < 4; ++e2) {
        long ee_ = eb + e2;
        short* xp = X + ee_ * 2432;
        if (ee_ < nchunk) {
            const short* rp = rad + ee_ * 1536;
            for (int i = t; i < 2432; i += 256) {
                int r = i >> 7, c = i & 127;
                int rr = (r < 9) ? r : ((r < 16) ? r - 4 : r - 7);
                float v = s_rot[e2][c * 20 + r] * b2f((unsigned short)rp[rr * 128 + c]);
                xp[i] = (short)f2b(v);
            }
        } else {
            for (int i = t; i < 2432; i += 256) xp[i] = 0;
        }
    }
}

// ---------------- templated MFMA GEMM phase (BK=128, ks fully unrolled) ----------
template<int Km, int Nm, int NACC>
__device__ __forceinline__ void conv_phase(
    const short* __restrict__ Xp, const long RS,
    const short* __restrict__ W, short* __restrict__ s_x, const int t,
    f32x4 (&acc)[NACC][4][2])
{
    const int w = t >> 6, l = t & 63, l15 = l & 15, lhi = l >> 4;
    const int swz = (l & 7) << 4;
    constexpr int NCHF = Km / 128;
    constexpr int TAIL = Km % 128;          // 0 or 64

    #pragma unroll
    for (int g = 0; g < NACC; ++g)
        #pragma unroll
        for (int mt = 0; mt < 4; ++mt)
            #pragma unroll
            for (int nt = 0; nt < 2; ++nt)
                acc[g][mt][nt] = (f32x4){0.f, 0.f, 0.f, 0.f};

    const int e_a = t >> 4,          k8_a = t & 15;
    const int e_b = (t + 512) >> 4,  k8_b = (t + 512) & 15;
    const int e_t = t >> 3,          k8_t = t & 7;

    uint4 ra0 = *(const uint4*)(Xp + (long)e_a * RS + (k8_a << 3));
    uint4 ra1 = *(const uint4*)(Xp + (long)e_b * RS + (k8_b << 3));

    auto mma_ks = [&](int kc0, int ks) {
        bf16x8 af[4];
        #pragma unroll
        for (int mt = 0; mt < 4; ++mt)
            af[mt] = *(const bf16x8*)((const char*)s_x + (mt * 16 + l15) * 256 +
                                      (((ks << 6) + (lhi << 4)) ^ swz));
        #pragma unroll
        for (int g = 0; g < NACC; ++g) {
            const int grp = w + (g << 3);
            if ((grp << 5) < Nm) {
                #pragma unroll
                for (int nt = 0; nt < 2; ++nt) {
                    const int col = (grp << 5) + (nt << 4) + l15;
                    bf16x8 bf = *(const bf16x8*)(W + (long)col * Km + kc0 + (ks << 5) + (lhi << 3));
                    #pragma unroll
                    for (int mt = 0; mt < 4; ++mt)
                        acc[g][mt][nt] = __builtin_amdgcn_mfma_f32_16x16x32_bf16(af[mt], bf, acc[g][mt][nt], 0, 0, 0);
                }
            }
        }
    };

    for (int ch = 0; ch < NCHF; ++ch) {
        __syncthreads();
        *(uint4*)((char*)s_x + e_a * 256 + ((k8_a << 4) ^ ((e_a & 7) << 4))) = ra0;
        *(uint4*)((char*)s_x + e_b * 256 + ((k8_b << 4) ^ ((e_b & 7) << 4))) = ra1;
        const int kc1 = (ch + 1) << 7;
        if (ch + 1 < NCHF) {
            ra0 = *(const uint4*)(Xp + (long)e_a * RS + kc1 + (k8_a << 3));
            ra1 = *(const uint4*)(Xp + (long)e_b * RS + kc1 + (k8_b << 3));
        } else if constexpr (TAIL != 0) {
            if (t < 512) ra0 = *(const uint4*)(Xp + (long)e_t * RS + kc1 + (k8_t << 3));
        }
        __syncthreads();
        const int kc0 = ch << 7;
        #pragma unroll
        for (int ks = 0; ks < 4; ++ks) mma_ks(kc0, ks);
    }
    if constexpr (TAIL != 0) {
        __syncthreads();
        if (t < 512)
            *(uint4*)((char*)s_x + e_t * 256 + ((k8_t << 4) ^ ((e_t & 7) << 4))) = ra0;
        __syncthreads();
        constexpr int kc0 = NCHF << 7;
        #pragma unroll
        for (int ks = 0; ks < TAIL / 32; ++ks) mma_ks(kc0, ks);
    }
}

// ---------------- conv1 + fused gate -> Z bf16 [E,1216] ----------------
__global__ __launch_bounds__(512)
void k_conv1(const short* __restrict__ X, const short* __restrict__ W0,
             const short* __restrict__ W1, const short* __restrict__ W2,
             const float* __restrict__ b1m0, short* __restrict__ Z)
{
    __shared__ __align__(16) short s_x[64 * 128];
    __shared__ __align__(16) short s_g[64 * 256];
    const int t = threadIdx.x, w = t >> 6, l = t & 63, l15 = l & 15, lhi = l >> 4;
    const long eb = (long)blockIdx.x * 64;

    // ===== m0: K=640 -> N=576 (320 out + 256 gating) =====
    {
        f32x4 acc[3][4][2];
        conv_phase<640, 576, 3>(X + eb * 2432, 2432, W0, s_x, t, acc);
        #pragma unroll
        for (int g = 0; g < 3; ++g) {
            int grp = w + g * 8;
            if (grp < 18) {
                #pragma unroll
                for (int nt = 0; nt < 2; ++nt) {
                    int jj = grp * 32 + nt * 16 + l15;
                    if (jj >= 320) {
                        float bias = b1m0[jj];
                        #pragma unroll
                        for (int mt = 0; mt < 4; ++mt)
                            #pragma unroll
                            for (int r = 0; r < 4; ++r) {
                                int e = mt * 16 + lhi * 4 + r;
                                s_g[e * 256 + (jj - 320)] = (short)f2b(sigm_(acc[g][mt][nt][r] + bias));
                            }
                    }
                }
            }
        }
        __syncthreads();
        #pragma unroll
        for (int g = 0; g < 3; ++g) {
            int grp = w + g * 8;
            if (grp < 10) {
                #pragma unroll
                for (int nt = 0; nt < 2; ++nt) {
                    int jj = grp * 32 + nt * 16 + l15;
                    float bias = b1m0[jj];
                    int r0 = jj >> 6;
                    #pragma unroll
                    for (int mt = 0; mt < 4; ++mt)
                        #pragma unroll
                        for (int r = 0; r < 4; ++r) {
                            int e = mt * 16 + lhi * 4 + r;
                            float v = acc[g][mt][nt][r] + bias;
                            float zv = (r0 == 0) ? silu_(v)
                                     : v * b2f((unsigned short)s_g[e * 256 + (r0 - 1) * 64 + (jj & 63)]);
                            Z[(eb + e) * 1216 + jj] = (short)f2b(zv);
                        }
                }
            }
        }
    }

    // ===== m1: K=1024 -> N=512, gate idx = j & 255 =====
    {
        f32x4 acc[2][4][2];
        conv_phase<1024, 512, 2>(X + eb * 2432 + 640, 2432, W1, s_x, t, acc);
        #pragma unroll
        for (int g = 0; g < 2; ++g) {
            int grp = w + g * 8;
            #pragma unroll
            for (int nt = 0; nt < 2; ++nt) {
                int jj = grp * 32 + nt * 16 + l15;
                #pragma unroll
                for (int mt = 0; mt < 4; ++mt)
                    #pragma unroll
                    for (int r = 0; r < 4; ++r) {
                        int e = mt * 16 + lhi * 4 + r;
                        float gt = b2f((unsigned short)s_g[e * 256 + (jj & 255)]);
                        Z[(eb + e) * 1216 + 320 + jj] = (short)f2b(acc[g][mt][nt][r] * gt);
                    }
            }
        }
    }

    // ===== m2: K=768 -> N=384, gate idx = 64 + (j mod 192) =====
    {
        f32x4 acc[2][4][2];
        conv_phase<768, 384, 2>(X + eb * 2432 + 1664, 2432, W2, s_x, t, acc);
        #pragma unroll
        for (int g = 0; g < 2; ++g) {
            int grp = w + g * 8;
            if (grp < 12) {
                #pragma unroll
                for (int nt = 0; nt < 2; ++nt) {
                    int jj = grp * 32 + nt * 16 + l15;
                    int jm = (jj >= 192) ? jj - 192 : jj;
                    #pragma unroll
                    for (int mt = 0; mt < 4; ++mt)
                        #pragma unroll
                        for (int r = 0; r < 4; ++r) {
                            int e = mt * 16 + lhi * 4 + r;
                            float gt = b2f((unsigned short)s_g[e * 256 + 64 + jm]);
                            Z[(eb + e) * 1216 + 832 + jj] = (short)f2b(acc[g][mt][nt][r] * gt);
                        }
                }
            }
        }
    }
}

// ---------------- conv2 -> Y2 bf16 [E,1216] ----------------
__global__ __launch_bounds__(512)
void k_conv2(const short* __restrict__ Zin, const short* __restrict__ V0,
             const short* __restrict__ V1, const short* __restrict__ V2,
             const float* __restrict__ b2m0, short* __restrict__ Y2)
{
    __shared__ __align__(16) short s_x[64 * 128];
    const int t = threadIdx.x, w = t >> 6, l = t & 63, l15 = l & 15, lhi = l >> 4;
    const long eb = (long)blockIdx.x * 64;

    {
        f32x4 acc[2][4][2];
        conv_phase<320, 320, 2>(Zin + eb * 1216, 1216, V0, s_x, t, acc);
        #pragma unroll
        for (int g = 0; g < 2; ++g) {
            int grp = w + g * 8;
            if (grp < 10) {
                #pragma unroll
                for (int nt = 0; nt < 2; ++nt) {
                    int jj = grp * 32 + nt * 16 + l15;
                    float bias = b2m0[jj];
                    #pragma unroll
                    for (int mt = 0; mt < 4; ++mt)
                        #pragma unroll
                        for (int r = 0; r < 4; ++r) {
                            int e = mt * 16 + lhi * 4 + r;
                            Y2[(eb + e) * 1216 + jj] = (short)f2b(acc[g][mt][nt][r] + bias);
                        }
                }
            }
        }
    }
    {
        f32x4 acc[2][4][2];
        conv_phase<512, 512, 2>(Zin + eb * 1216 + 320, 1216, V1, s_x, t, acc);
        #pragma unroll
        for (int g = 0; g < 2; ++g) {
            int grp = w + g * 8;
            #pragma unroll
            for (int nt = 0; nt < 2; ++nt) {
                int jj = grp * 32 + nt * 16 + l15;
                #pragma unroll
                for (int mt = 0; mt < 4; ++mt)
                    #pragma unroll
                    for (int r = 0; r < 4; ++r) {
                        int e = mt * 16 + lhi * 4 + r;
                        Y2[(eb + e) * 1216 + 320 + jj] = (short)f2b(acc[g][mt][nt][r]);
                    }
            }
        }
    }
    {
        f32x4 acc[2][4][2];
        conv_phase<384, 384, 2>(Zin + eb * 1216 + 832, 1216, V2, s_x, t, acc);
        #pragma unroll
        for (int g = 0; g < 2; ++g) {
            int grp = w + g * 8;
            if (grp < 12) {
                #pragma unroll
                for (int nt = 0; nt < 2; ++nt) {
                    int jj = grp * 32 + nt * 16 + l15;
                    #pragma unroll
                    for (int mt = 0; mt < 4; ++mt)
                        #pragma unroll
                        for (int r = 0; r < 4; ++r) {
                            int e = mt * 16 + lhi * 4 + r;
                            Y2[(eb + e) * 1216 + 832 + jj] = (short)f2b(acc[g][mt][nt][r]);
                        }
                }
            }
        }
    }
}

// ---------------- node-major: wigner_inv + envelope + segment sum (no atomics) ----
__global__ __launch_bounds__(256)
void k_invn(const short* __restrict__ Y2, const float* __restrict__ winv,
            const float* __restrict__ env, const int* __restrict__ cnt,
            const int* __restrict__ off, const int* __restrict__ perm,
            float* __restrict__ out, long e0)
{
    __shared__ __align__(16) short s_y[2][1216];
    __shared__ float s_wv[2][476];
    const int t = threadIdx.x;
    const int n = blockIdx.x;
    const int deg = cnt[n], start = off[n];

    float acc[7];
    #pragma unroll
    for (int j = 0; j < 7; ++j) acc[j] = 0.f;

    auto stage = [&](int i, int b) {
        int el = perm[start + i];
        long ge = e0 + el;
        if (t < 152) ((uint4*)s_y[b])[t] = *(const uint4*)(Y2 + (long)el * 1216 + t * 8);
        for (int p = t; p < 475; p += 256) s_wv[b][p] = winv[ge * 475 + p];
        if (t == 0) s_wv[b][475] = env[ge];
    };

    if (deg > 0) stage(0, 0);
    for (int i = 0; i < deg; ++i) {
        __syncthreads();
        if (i + 1 < deg) stage(i + 1, (i + 1) & 1);
        const short* sy = s_y[i & 1];
        const float* sw = s_wv[i & 1];
        float ev = sw[475];
        #pragma unroll
        for (int j = 0; j < 7; ++j) {
            int f = t + j * 256;
            if (f < 1600) {
                int r = f >> 6, c = f & 63;
                float a = 0.f;
                #pragma unroll
                for (int k = 0; k < 19; ++k)
                    a = fmaf(sw[r * 19 + k], b2f((unsigned short)sy[k * 64 + c]), a);
                acc[j] = fmaf(a, ev, acc[j]);
            }
        }
    }
    #pragma unroll
    for (int j = 0; j < 7; ++j) {
        int f = t + j * 256;
        if (f < 1600) out[(long)n * 1600 + f] += acc[j];
    }
}

extern "C" void kernel_launch(void* const* d_in, const int* in_sizes, int n_in,
                              void* d_out, int out_size, void* d_ws, size_t ws_size,
                              hipStream_t stream)
{
    const float* nf   = (const float*)d_in[0];
    const float* ee   = (const float*)d_in[1];
    const float* wig  = (const float*)d_in[2];
    const float* winv = (const float*)d_in[3];
    const float* env  = (const float*)d_in[4];
    const float* rw1  = (const float*)d_in[5];
    const float* rb1  = (const float*)d_in[6];
    const float* rw2  = (const float*)d_in[7];
    const float* rb2  = (const float*)d_in[8];
    const float* w1m0 = (const float*)d_in[9];
    const float* b1m0 = (const float*)d_in[10];
    const float* w1r1 = (const float*)d_in[11];
    const float* w1i1 = (const float*)d_in[12];
    const float* w1r2 = (const float*)d_in[13];
    const float* w1i2 = (const float*)d_in[14];
    const float* w2m0 = (const float*)d_in[15];
    const float* b2m0 = (const float*)d_in[16];
    const float* w2r1 = (const float*)d_in[17];
    const float* w2i1 = (const float*)d_in[18];
    const float* w2r2 = (const float*)d_in[19];
    const float* w2i2 = (const float*)d_in[20];
    const int*   snd  = (const int*)d_in[21];
    const int*   rcv  = (const int*)d_in[22];
    float* out = (float*)d_out;

    const long E = in_sizes[21];

    short* Wb  = (short*)d_ws;
    short* nfT = Wb + W_TOTAL;
    int* cnt   = (int*)(nfT + NFT_ELEMS);
    int* off   = cnt + 2512;
    int* nxt   = off + 2512;
    int* perm  = nxt + 2512;

    // per-edge ws: perm 4B + X 4864B (reused by Wg and Y2) + rad 3072B (reused by Z)
    const size_t fixed = (size_t)W_TOTAL * 2 + (size_t)NFT_ELEMS * 2 + 3 * 2512 * 4;
    long cap = (ws_size > fixed) ? (long)((ws_size - fixed) / 7940) : 64;
    long chunk = (cap / 64) * 64;
    if (chunk < 64) chunk = 64;
    long Epad = ((E + 63) / 64) * 64;
    if (chunk > Epad) chunk = Epad;

    short* Xc = (short*)(perm + chunk);     // chunk*2432; holds Wg, then X, then Y2
    short* Rc = Xc + chunk * 2432;          // chunk*1536; holds rad, then Z

    hipMemsetAsync(d_out, 0, (size_t)out_size * sizeof(float), stream);
    k_prep<<<(int)((W_TOTAL + 511) / 512), 512, 0, stream>>>(
        w1m0, w1r1, w1i1, w1r2, w1i2, w2m0, w2r1, w2i1, w2r2, w2i2, rw2, Wb);
    k_nft<<<NNODES, 256, 0, stream>>>(nf, nfT);

    for (long base = 0; base < E; base += chunk) {
        long n = E - base; if (n > chunk) n = chunk;
        int nb  = (int)((n + 63) / 64);
        int nbe = (int)((n + 255) / 256);

        hipMemsetAsync(cnt, 0, NNODES * sizeof(int), stream);
        k_hist<<<nbe, 256, 0, stream>>>(rcv, cnt, base, n);
        k_scan<<<1, 256, 0, stream>>>(cnt, off, nxt);
        k_scat<<<nbe, 256, 0, stream>>>(rcv, nxt, perm, base, n);

        k_rad  <<<nb * 2, 512, 0, stream>>>(ee, rw1, rb1, rb2, Wb + OFF_RW2T, Rc, base, E);
        k_wig  <<<(int)((n + 7) / 8), 256, 0, stream>>>(wig, Xc, base, n);
        k_rot2 <<<nb * 16, 256, 0, stream>>>(nfT, Rc, snd, rcv, Xc, base, n);
        k_conv1<<<nb,     512, 0, stream>>>(Xc, Wb + OFF_W1T, Wb + OFF_W1C1, Wb + OFF_W1C2, b1m0, Rc);
        k_conv2<<<nb,     512, 0, stream>>>(Rc, Wb + OFF_V0T, Wb + OFF_V1C, Wb + OFF_V2C, b2m0, Xc);
        k_invn <<<NNODES, 256, 0, stream>>>(Xc, winv, env, cnt, off, perm, out, base);
    }
    (void)n_in;
}

// Round 5
// 1371.228 us; speedup vs baseline: 4.0415x; 1.0664x over previous
//
#include <hip/hip_runtime.h>

// SO(2)-equivariant edge conv — bf16 MFMA pipeline, round 5.
// X per edge (2432 bf16): m0 rows0-4 [0,640) | m1 re+im [640,1664) | m2 [1664,2432)
// Zr per edge (1536-short stride in Rc): raw conv1 out [0,1216) + sigmoid gates [1216,1472)
// Y2 per edge (1216 bf16, stride 1216 in Xc region).
// Weights transposed [N][K] bf16; complex convs combined: W=[[wr,wi],[-wi,wr]].
// NEW: gate-deferral (gates applied in conv2 A-staging) -> conv phases independent ->
// grid (nb,3); double-buffered LDS, 1 barrier per 128-K chunk.

typedef __attribute__((ext_vector_type(8))) short bf16x8;
typedef __attribute__((ext_vector_type(4))) float f32x4;

union U8 { uint4 v; unsigned short s[8]; };

__device__ __forceinline__ unsigned short f2b(float f) {
    unsigned u = __float_as_uint(f);
    unsigned r = (u + 0x7FFFu + ((u >> 16) & 1u)) >> 16;
    return (unsigned short)r;
}
__device__ __forceinline__ float b2f(unsigned short h) {
    return __uint_as_float(((unsigned)h) << 16);
}
__device__ __forceinline__ float sigm_(float x){ return 1.0f/(1.0f+__expf(-x)); }
__device__ __forceinline__ float silu_(float x){ return x/(1.0f+__expf(-x)); }

// weight region offsets (bf16 elems) in ws
#define OFF_W1T   0L
#define OFF_W1C1  368640L
#define OFF_W1C2  892928L
#define OFF_V0T   1187840L
#define OFF_V1C   1290240L
#define OFF_V2C   1552384L
#define OFF_RW2T  1699840L
#define W_TOTAL   1798144L
#define NNODES    2500
#define NFT_ELEMS (2500L * 2048L)

// ---------------- weight prep ----------------
__global__ void k_prep(const float* __restrict__ w1m0, const float* __restrict__ w1r1,
                       const float* __restrict__ w1i1, const float* __restrict__ w1r2,
                       const float* __restrict__ w1i2, const float* __restrict__ w2m0,
                       const float* __restrict__ w2r1, const float* __restrict__ w2i1,
                       const float* __restrict__ w2r2, const float* __restrict__ w2i2,
                       const float* __restrict__ rw2, short* __restrict__ W)
{
    long i = (long)blockIdx.x * blockDim.x + threadIdx.x;
    if (i >= W_TOTAL) return;
    float v;
    if (i < OFF_W1C1) {                    // W1T [576][640]
        long n = i / 640, k = i - n * 640;
        v = w1m0[k * 576 + n];
    } else if (i < OFF_W1C2) {             // W1c1 [512][1024]
        long j = i - OFF_W1C1; int n = (int)(j >> 10), k = (int)(j & 1023);
        v = (n < 256) ? ((k < 512) ? w1r1[k*256 + n] : -w1i1[(k-512)*256 + n])
                      : ((k < 512) ? w1i1[k*256 + (n-256)] : w1r1[(k-512)*256 + (n-256)]);
    } else if (i < OFF_V0T) {              // W1c2 [384][768]
        long j = i - OFF_W1C2; int n = (int)(j / 768), k = (int)(j - (long)n * 768);
        v = (n < 192) ? ((k < 384) ? w1r2[k*192 + n] : -w1i2[(k-384)*192 + n])
                      : ((k < 384) ? w1i2[k*192 + (n-192)] : w1r2[(k-384)*192 + (n-192)]);
    } else if (i < OFF_V1C) {              // V0T [320][320]
        long j = i - OFF_V0T; int n = (int)(j / 320), k = (int)(j - (long)n * 320);
        v = w2m0[k * 320 + n];
    } else if (i < OFF_V2C) {              // V1c [512][512]
        long j = i - OFF_V1C; int n = (int)(j >> 9), k = (int)(j & 511);
        v = (n < 256) ? ((k < 256) ? w2r1[k*256 + n] : -w2i1[(k-256)*256 + n])
                      : ((k < 256) ? w2i1[k*256 + (n-256)] : w2r1[(k-256)*256 + (n-256)]);
    } else if (i < OFF_RW2T) {             // V2c [384][384]
        long j = i - OFF_V2C; int n = (int)(j / 384), k = (int)(j - (long)n * 384);
        v = (n < 192) ? ((k < 192) ? w2r2[k*192 + n] : -w2i2[(k-192)*192 + n])
                      : ((k < 192) ? w2i2[k*192 + (n-192)] : w2r2[(k-192)*192 + (n-192)]);
    } else {                               // RW2T [1536][64]
        long j = i - OFF_RW2T; int n = (int)(j >> 6), d = (int)(j & 63);
        v = rw2[d * 1536 + n];
    }
    W[i] = (short)f2b(v);
}

// ---------------- node-feature transpose ----------------
__global__ __launch_bounds__(256)
void k_nft(const float* __restrict__ nf, short* __restrict__ nfT)
{
    __shared__ float s_nf[25 * 65];
    const int t = threadIdx.x;
    const long nn = blockIdx.x;
    for (int p = t; p < 1600; p += 256) {
        int r = p >> 6, c = p & 63;
        s_nf[r * 65 + c] = nf[nn * 1600 + p];
    }
    __syncthreads();
    for (int i = t; i < 2048; i += 256) {
        int c = i >> 5, k = i & 31;
        float v = (k < 25) ? s_nf[k * 65 + c] : 0.f;
        nfT[nn * 2048 + i] = (short)f2b(v);
    }
}

// ---------------- wigner -> bf16 padded [19][32], aliased into X rows ----------
__global__ __launch_bounds__(256)
void k_wig(const float* __restrict__ wig, short* __restrict__ Xc, long e0, long n)
{
    const int t = threadIdx.x;
    const long eb = (long)blockIdx.x * 8;
    for (int el = 0; el < 8; ++el) {
        long e = eb + el;
        if (e >= n) break;
        const float* wp = wig + (e0 + e) * 475;
        short* dst = Xc + e * 2432;
        for (int p = t; p < 608; p += 256) {
            int r = p >> 5, k = p & 31;
            dst[p] = (short)f2b((k < 25) ? wp[r * 25 + k] : 0.f);
        }
    }
}

// ---------------- CSR build ----------------
__global__ void k_hist(const int* __restrict__ rcv, int* __restrict__ cnt, long e0, long n)
{
    long e = (long)blockIdx.x * 256 + threadIdx.x;
    if (e < n) atomicAdd(&cnt[rcv[e0 + e]], 1);
}

__global__ __launch_bounds__(256)
void k_scan(const int* __restrict__ cnt, int* __restrict__ off, int* __restrict__ nxt)
{
    __shared__ int part[256];
    const int t = threadIdx.x;
    const int base = t * 10;
    int loc[10]; int s = 0;
    #pragma unroll
    for (int j = 0; j < 10; ++j) {
        int idx = base + j;
        int v = (idx < NNODES) ? cnt[idx] : 0;
        loc[j] = s; s += v;
    }
    part[t] = s;
    __syncthreads();
    for (int d = 1; d < 256; d <<= 1) {
        int v = part[t];
        int u = (t >= d) ? part[t - d] : 0;
        __syncthreads();
        part[t] = v + u;
        __syncthreads();
    }
    int excl = (t == 0) ? 0 : part[t - 1];
    #pragma unroll
    for (int j = 0; j < 10; ++j) {
        int idx = base + j;
        if (idx < NNODES) { int o = excl + loc[j]; off[idx] = o; nxt[idx] = o; }
    }
}

__global__ void k_scat(const int* __restrict__ rcv, int* __restrict__ nxt,
                       int* __restrict__ perm, long e0, long n)
{
    long e = (long)blockIdx.x * 256 + threadIdx.x;
    if (e < n) {
        int p = atomicAdd(&nxt[rcv[e0 + e]], 1);
        perm[p] = (int)e;
    }
}

// ---------------- radial MLP ----------------
__global__ __launch_bounds__(512)
void k_rad(const float* __restrict__ ee, const float* __restrict__ rw1,
           const float* __restrict__ rb1, const float* __restrict__ rb2,
           const short* __restrict__ RW2T, short* __restrict__ rad,
           long e0, long Etot)
{
    __shared__ __align__(16) short s_h[32 * 64];
    const int t = threadIdx.x, w = t >> 6, l = t & 63, l15 = l & 15, lhi = l >> 4;
    const long eb = (long)blockIdx.x * 32;

    #pragma unroll
    for (int j = 0; j < 4; ++j) {
        int i = t + j * 512;
        int e = i >> 6, d = i & 63;
        long ge = e0 + eb + e;
        float a = rb1[d];
        if (ge < Etot) {
            const float* ep = ee + ge * 128;
            #pragma unroll 16
            for (int dd = 0; dd < 128; ++dd) a = fmaf(ep[dd], rw1[dd * 64 + d], a);
            a = silu_(a);
        } else a = 0.f;
        *(short*)((char*)s_h + e * 128 + ((d * 2) ^ ((e & 7) << 4))) = (short)f2b(a);
    }
    __syncthreads();

    f32x4 acc[6][2][2];
    #pragma unroll
    for (int g = 0; g < 6; ++g)
        #pragma unroll
        for (int mt = 0; mt < 2; ++mt)
            #pragma unroll
            for (int nt = 0; nt < 2; ++nt)
                acc[g][mt][nt] = (f32x4){0.f, 0.f, 0.f, 0.f};

    #pragma unroll
    for (int ks = 0; ks < 2; ++ks) {
        bf16x8 af[2];
        #pragma unroll
        for (int mt = 0; mt < 2; ++mt)
            af[mt] = *(const bf16x8*)((const char*)s_h + (mt * 16 + l15) * 128 +
                                      (((ks << 6) + (lhi << 4)) ^ ((l & 7) << 4)));
        #pragma unroll
        for (int g = 0; g < 6; ++g) {
            int grp = w + g * 8;
            #pragma unroll
            for (int nt = 0; nt < 2; ++nt) {
                int col = grp * 32 + nt * 16 + l15;
                bf16x8 bf = *(const bf16x8*)(RW2T + (long)col * 64 + (ks << 5) + (lhi << 3));
                #pragma unroll
                for (int mt = 0; mt < 2; ++mt)
                    acc[g][mt][nt] = __builtin_amdgcn_mfma_f32_16x16x32_bf16(af[mt], bf, acc[g][mt][nt], 0, 0, 0);
            }
        }
    }
    #pragma unroll
    for (int g = 0; g < 6; ++g)
        #pragma unroll
        for (int nt = 0; nt < 2; ++nt) {
            int col = (w + g * 8) * 32 + nt * 16 + l15;
            float bias = rb2[col];
            #pragma unroll
            for (int mt = 0; mt < 2; ++mt)
                #pragma unroll
                for (int r = 0; r < 4; ++r) {
                    int e = mt * 16 + lhi * 4 + r;
                    rad[(eb + e) * 1536 + col] = (short)f2b(acc[g][mt][nt][r] + bias);
                }
        }
}

// ---------------- MFMA wigner rotate ----------------
__global__ __launch_bounds__(256)
void k_rot2(const short* __restrict__ nfT, const short* __restrict__ rad,
            const int* __restrict__ snd, const int* __restrict__ rcv,
            short* __restrict__ X, long e0, long nchunk)
{
    __shared__ float s_rot[4][128 * 20];
    const int t = threadIdx.x, w = t >> 6, l = t & 63, l15 = l & 15, lhi = l >> 4;
    const long eb = (long)blockIdx.x * 4;
    const long el = eb + w;

    if (el < nchunk) {
        long ge = e0 + el;
        int n0 = snd[ge], n1 = rcv[ge];
        const short* wg = X + el * 2432;
        bf16x8 a0 = *(const bf16x8*)(wg + l15 * 32 + lhi * 8);
        bf16x8 a1 = {0,0,0,0,0,0,0,0};
        if (l15 < 3) a1 = *(const bf16x8*)(wg + (16 + l15) * 32 + lhi * 8);

        f32x4 acc0[8], acc1[8];
        #pragma unroll
        for (int nt = 0; nt < 8; ++nt) {
            acc0[nt] = (f32x4){0.f, 0.f, 0.f, 0.f};
            acc1[nt] = (f32x4){0.f, 0.f, 0.f, 0.f};
        }
        #pragma unroll
        for (int nt = 0; nt < 8; ++nt) {
            int col = nt * 16 + l15;
            bf16x8 b = *(const bf16x8*)(nfT + (long)(col < 64 ? n0 : n1) * 2048 +
                                        (long)(col & 63) * 32 + (lhi << 3));
            acc0[nt] = __builtin_amdgcn_mfma_f32_16x16x32_bf16(a0, b, acc0[nt], 0, 0, 0);
            acc1[nt] = __builtin_amdgcn_mfma_f32_16x16x32_bf16(a1, b, acc1[nt], 0, 0, 0);
        }
        #pragma unroll
        for (int nt = 0; nt < 8; ++nt) {
            int col = nt * 16 + l15;
            *(f32x4*)&s_rot[w][col * 20 + lhi * 4] = acc0[nt];
            if (lhi == 0) *(f32x4*)&s_rot[w][col * 20 + 16] = acc1[nt];
        }
    }
    __syncthreads();

    #pragma unroll
    for (int e2 = 0; e2 < 4; ++e2) {
        long ee_ = eb + e2;
        short* xp = X + ee_ * 2432;
        if (ee_ < nchunk) {
            const short* rp = rad + ee_ * 1536;
            for (int i = t; i < 2432; i += 256) {
                int r = i >> 7, c = i & 127;
                int rr = (r < 9) ? r : ((r < 16) ? r - 4 : r - 7);
                float v = s_rot[e2][c * 20 + r] * b2f((unsigned short)rp[rr * 128 + c]);
                xp[i] = (short)f2b(v);
            }
        } else {
            for (int i = t; i < 2432; i += 256) xp[i] = 0;
        }
    }
}

// ---------------- dbuf MFMA GEMM phase: 1 barrier per 128-K chunk ----------------
// A: [64 edges][Km] bf16 at Xp (+e*RS); GMODE applies gates during staging:
//   0 none | 1 conv2-m0 (silu row0, gate rows1-4) | 2 conv2-m1 (g[k&255]) | 3 conv2-m2 (g[64+k%192])
// gates at Xp + e*RS + gofs. B: W [Nm][Km] transposed, 16B frags from L2.
template<int Km, int Nm, int NACC, int GMODE>
__device__ __forceinline__ void conv_phase(
    const short* __restrict__ Xp, const long RS, const int gofs,
    const short* __restrict__ W, short* __restrict__ s_x, const int t,
    f32x4 (&acc)[NACC][4][2])
{
    const int w = t >> 6, l = t & 63, l15 = l & 15, lhi = l >> 4;
    const int swz = (l & 7) << 4;
    constexpr int FCH = Km / 128;
    constexpr int TAIL = Km % 128;          // 0 or 64

    #pragma unroll
    for (int g = 0; g < NACC; ++g)
        #pragma unroll
        for (int mt = 0; mt < 4; ++mt)
            #pragma unroll
            for (int nt = 0; nt < 2; ++nt)
                acc[g][mt][nt] = (f32x4){0.f, 0.f, 0.f, 0.f};

    const int e_a = t >> 4,          k8_a = t & 15;
    const int e_b = (t + 512) >> 4,  k8_b = (t + 512) & 15;
    const int e_t = t >> 3,          k8_t = t & 7;

    auto ld = [&](int e, int kg) -> uint4 {
        const short* rowp = Xp + (long)e * RS;
        uint4 z = *(const uint4*)(rowp + kg);
        if constexpr (GMODE == 0) return z;
        U8 zz; zz.v = z; U8 r;
        if constexpr (GMODE == 1) {
            int row = kg >> 6;
            if (row == 0) {
                #pragma unroll
                for (int i = 0; i < 8; ++i) r.s[i] = f2b(silu_(b2f(zz.s[i])));
            } else {
                U8 gg; gg.v = *(const uint4*)(rowp + gofs + (row - 1) * 64 + (kg & 63));
                #pragma unroll
                for (int i = 0; i < 8; ++i) r.s[i] = f2b(b2f(zz.s[i]) * b2f(gg.s[i]));
            }
        } else if constexpr (GMODE == 2) {
            U8 gg; gg.v = *(const uint4*)(rowp + gofs + (kg & 255));
            #pragma unroll
            for (int i = 0; i < 8; ++i) r.s[i] = f2b(b2f(zz.s[i]) * b2f(gg.s[i]));
        } else {
            int gi = 64 + kg - ((kg >= 192) ? 192 : 0);
            U8 gg; gg.v = *(const uint4*)(rowp + gofs + gi);
            #pragma unroll
            for (int i = 0; i < 8; ++i) r.s[i] = f2b(b2f(zz.s[i]) * b2f(gg.s[i]));
        }
        return r.v;
    };

    auto mma_ks = [&](const short* buf, int kc0, int ks) {
        bf16x8 af[4];
        #pragma unroll
        for (int mt = 0; mt < 4; ++mt)
            af[mt] = *(const bf16x8*)((const char*)buf + (mt * 16 + l15) * 256 +
                                      (((ks << 6) + (lhi << 4)) ^ swz));
        #pragma unroll
        for (int g = 0; g < NACC; ++g) {
            const int grp = w + (g << 3);
            if ((grp << 5) < Nm) {
                #pragma unroll
                for (int nt = 0; nt < 2; ++nt) {
                    const int col = (grp << 5) + (nt << 4) + l15;
                    bf16x8 bf = *(const bf16x8*)(W + (long)col * Km + kc0 + (ks << 5) + (lhi << 3));
                    #pragma unroll
                    for (int mt = 0; mt < 4; ++mt)
                        acc[g][mt][nt] = __builtin_amdgcn_mfma_f32_16x16x32_bf16(af[mt], bf, acc[g][mt][nt], 0, 0, 0);
                }
            }
        }
    };

    uint4 ra0 = ld(e_a, (k8_a << 3));
    uint4 ra1 = ld(e_b, (k8_b << 3));
    #pragma unroll
    for (int ch = 0; ch < FCH; ++ch) {
        short* buf = s_x + (ch & 1) * 8192;
        // writes target buf[ch&1]; any wave still computing is in chunk ch-1 on the
        // OTHER buffer (all passed the ch-1 barrier), so no barrier needed before writes.
        *(uint4*)((char*)buf + e_a * 256 + ((k8_a << 4) ^ ((e_a & 7) << 4))) = ra0;
        *(uint4*)((char*)buf + e_b * 256 + ((k8_b << 4) ^ ((e_b & 7) << 4))) = ra1;
        if (ch + 1 < FCH) {
            ra0 = ld(e_a, ((ch + 1) << 7) + (k8_a << 3));
            ra1 = ld(e_b, ((ch + 1) << 7) + (k8_b << 3));
        } else if constexpr (TAIL != 0) {
            ra0 = ld(e_t, (FCH << 7) + (k8_t << 3));
        }
        __syncthreads();
        #pragma unroll
        for (int ks = 0; ks < 4; ++ks) mma_ks(buf, ch << 7, ks);
    }
    if constexpr (TAIL != 0) {
        short* buf = s_x + (FCH & 1) * 8192;
        *(uint4*)((char*)buf + e_t * 256 + ((k8_t << 4) ^ ((e_t & 7) << 4))) = ra0;
        __syncthreads();
        #pragma unroll
        for (int ks = 0; ks < TAIL / 32; ++ks) mma_ks(buf, FCH << 7, ks);
    }
}

// ---------------- conv1 (phase-split, raw out + sigmoid gates) ----------------
__global__ __launch_bounds__(512)
void k_conv1(const short* __restrict__ X, const short* __restrict__ W0,
             const short* __restrict__ W1, const short* __restrict__ W2,
             const float* __restrict__ b1m0, short* __restrict__ Zr)
{
    __shared__ __align__(16) short s_x[2 * 64 * 128];
    const int t = threadIdx.x, w = t >> 6, l = t & 63, l15 = l & 15, lhi = l >> 4;
    const long eb = (long)blockIdx.x * 64;
    const int ph = blockIdx.y;

    if (ph == 0) {          // m0: K=640 -> N=576 (320 raw + 256 gate logits)
        f32x4 acc[3][4][2];
        conv_phase<640, 576, 3, 0>(X + eb * 2432, 2432, 0, W0, s_x, t, acc);
        #pragma unroll
        for (int g = 0; g < 3; ++g) {
            int grp = w + g * 8;
            if (grp < 18) {
                #pragma unroll
                for (int nt = 0; nt < 2; ++nt) {
                    int jj = grp * 32 + nt * 16 + l15;
                    float bias = b1m0[jj];
                    #pragma unroll
                    for (int mt = 0; mt < 4; ++mt)
                        #pragma unroll
                        for (int r = 0; r < 4; ++r) {
                            int e = mt * 16 + lhi * 4 + r;
                            float v = acc[g][mt][nt][r] + bias;
                            if (jj < 320)
                                Zr[(eb + e) * 1536 + jj] = (short)f2b(v);
                            else
                                Zr[(eb + e) * 1536 + 1216 + (jj - 320)] = (short)f2b(sigm_(v));
                        }
                }
            }
        }
    } else if (ph == 1) {   // m1: K=1024 -> N=512 raw
        f32x4 acc[2][4][2];
        conv_phase<1024, 512, 2, 0>(X + eb * 2432 + 640, 2432, 0, W1, s_x, t, acc);
        #pragma unroll
        for (int g = 0; g < 2; ++g) {
            int grp = w + g * 8;
            #pragma unroll
            for (int nt = 0; nt < 2; ++nt) {
                int jj = grp * 32 + nt * 16 + l15;
                #pragma unroll
                for (int mt = 0; mt < 4; ++mt)
                    #pragma unroll
                    for (int r = 0; r < 4; ++r) {
                        int e = mt * 16 + lhi * 4 + r;
                        Zr[(eb + e) * 1536 + 320 + jj] = (short)f2b(acc[g][mt][nt][r]);
                    }
            }
        }
    } else {                // m2: K=768 -> N=384 raw
        f32x4 acc[2][4][2];
        conv_phase<768, 384, 2, 0>(X + eb * 2432 + 1664, 2432, 0, W2, s_x, t, acc);
        #pragma unroll
        for (int g = 0; g < 2; ++g) {
            int grp = w + g * 8;
            if (grp < 12) {
                #pragma unroll
                for (int nt = 0; nt < 2; ++nt) {
                    int jj = grp * 32 + nt * 16 + l15;
                    #pragma unroll
                    for (int mt = 0; mt < 4; ++mt)
                        #pragma unroll
                        for (int r = 0; r < 4; ++r) {
                            int e = mt * 16 + lhi * 4 + r;
                            Zr[(eb + e) * 1536 + 832 + jj] = (short)f2b(acc[g][mt][nt][r]);
                        }
                }
            }
        }
    }
}

// ---------------- conv2 (phase-split, gates applied in staging) ----------------
__global__ __launch_bounds__(512)
void k_conv2(const short* __restrict__ Zr, const short* __restrict__ V0,
             const short* __restrict__ V1, const short* __restrict__ V2,
             const float* __restrict__ b2m0, short* __restrict__ Y2)
{
    __shared__ __align__(16) short s_x[2 * 64 * 128];
    const int t = threadIdx.x, w = t >> 6, l = t & 63, l15 = l & 15, lhi = l >> 4;
    const long eb = (long)blockIdx.x * 64;
    const int ph = blockIdx.y;

    if (ph == 0) {          // m0: K=320 -> N=320 (+bias)
        f32x4 acc[2][4][2];
        conv_phase<320, 320, 2, 1>(Zr + eb * 1536, 1536, 1216, V0, s_x, t, acc);
        #pragma unroll
        for (int g = 0; g < 2; ++g) {
            int grp = w + g * 8;
            if (grp < 10) {
                #pragma unroll
                for (int nt = 0; nt < 2; ++nt) {
                    int jj = grp * 32 + nt * 16 + l15;
                    float bias = b2m0[jj];
                    #pragma unroll
                    for (int mt = 0; mt < 4; ++mt)
                        #pragma unroll
                        for (int r = 0; r < 4; ++r) {
                            int e = mt * 16 + lhi * 4 + r;
                            Y2[(eb + e) * 1216 + jj] = (short)f2b(acc[g][mt][nt][r] + bias);
                        }
                }
            }
        }
    } else if (ph == 1) {   // m1: K=512 -> N=512
        f32x4 acc[2][4][2];
        conv_phase<512, 512, 2, 2>(Zr + eb * 1536 + 320, 1536, 1216 - 320, V1, s_x, t, acc);
        #pragma unroll
        for (int g = 0; g < 2; ++g) {
            int grp = w + g * 8;
            #pragma unroll
            for (int nt = 0; nt < 2; ++nt) {
                int jj = grp * 32 + nt * 16 + l15;
                #pragma unroll
                for (int mt = 0; mt < 4; ++mt)
                    #pragma unroll
                    for (int r = 0; r < 4; ++r) {
                        int e = mt * 16 + lhi * 4 + r;
                        Y2[(eb + e) * 1216 + 320 + jj] = (short)f2b(acc[g][mt][nt][r]);
                    }
            }
        }
    } else {                // m2: K=384 -> N=384
        f32x4 acc[2][4][2];
        conv_phase<384, 384, 2, 3>(Zr + eb * 1536 + 832, 1536, 1216 - 832, V2, s_x, t, acc);
        #pragma unroll
        for (int g = 0; g < 2; ++g) {
            int grp = w + g * 8;
            if (grp < 12) {
                #pragma unroll
                for (int nt = 0; nt < 2; ++nt) {
                    int jj = grp * 32 + nt * 16 + l15;
                    #pragma unroll
                    for (int mt = 0; mt < 4; ++mt)
                        #pragma unroll
                        for (int r = 0; r < 4; ++r) {
                            int e = mt * 16 + lhi * 4 + r;
                            Y2[(eb + e) * 1216 + 832 + jj] = (short)f2b(acc[g][mt][nt][r]);
                        }
                }
            }
        }
    }
}

// ---------------- node-major wigner_inv + envelope + segment sum ----------------
__global__ __launch_bounds__(256)
void k_invn(const short* __restrict__ Y2, const float* __restrict__ winv,
            const float* __restrict__ env, const int* __restrict__ cnt,
            const int* __restrict__ off, const int* __restrict__ perm,
            float* __restrict__ out, long e0)
{
    __shared__ __align__(16) short s_y[2][1216];
    __shared__ float s_wv[2][476];
    const int t = threadIdx.x;
    const int n = blockIdx.x;
    const int deg = cnt[n], start = off[n];

    float acc[7];
    #pragma unroll
    for (int j = 0; j < 7; ++j) acc[j] = 0.f;

    auto stage = [&](int i, int b) {
        int el = perm[start + i];
        long ge = e0 + el;
        if (t < 152) ((uint4*)s_y[b])[t] = *(const uint4*)(Y2 + (long)el * 1216 + t * 8);
        for (int p = t; p < 475; p += 256) s_wv[b][p] = winv[ge * 475 + p];
        if (t == 0) s_wv[b][475] = env[ge];
    };

    if (deg > 0) stage(0, 0);
    for (int i = 0; i < deg; ++i) {
        __syncthreads();
        if (i + 1 < deg) stage(i + 1, (i + 1) & 1);
        const short* sy = s_y[i & 1];
        const float* sw = s_wv[i & 1];
        float ev = sw[475];
        #pragma unroll
        for (int j = 0; j < 7; ++j) {
            int f = t + j * 256;
            if (f < 1600) {
                int r = f >> 6, c = f & 63;
                float a = 0.f;
                #pragma unroll
                for (int k = 0; k < 19; ++k)
                    a = fmaf(sw[r * 19 + k], b2f((unsigned short)sy[k * 64 + c]), a);
                acc[j] = fmaf(a, ev, acc[j]);
            }
        }
    }
    #pragma unroll
    for (int j = 0; j < 7; ++j) {
        int f = t + j * 256;
        if (f < 1600) out[(long)n * 1600 + f] += acc[j];
    }
}

extern "C" void kernel_launch(void* const* d_in, const int* in_sizes, int n_in,
                              void* d_out, int out_size, void* d_ws, size_t ws_size,
                              hipStream_t stream)
{
    const float* nf   = (const float*)d_in[0];
    const float* ee   = (const float*)d_in[1];
    const float* wig  = (const float*)d_in[2];
    const float* winv = (const float*)d_in[3];
    const float* env  = (const float*)d_in[4];
    const float* rw1  = (const float*)d_in[5];
    const float* rb1  = (const float*)d_in[6];
    const float* rw2  = (const float*)d_in[7];
    const float* rb2  = (const float*)d_in[8];
    const float* w1m0 = (const float*)d_in[9];
    const float* b1m0 = (const float*)d_in[10];
    const float* w1r1 = (const float*)d_in[11];
    const float* w1i1 = (const float*)d_in[12];
    const float* w1r2 = (const float*)d_in[13];
    const float* w1i2 = (const float*)d_in[14];
    const float* w2m0 = (const float*)d_in[15];
    const float* b2m0 = (const float*)d_in[16];
    const float* w2r1 = (const float*)d_in[17];
    const float* w2i1 = (const float*)d_in[18];
    const float* w2r2 = (const float*)d_in[19];
    const float* w2i2 = (const float*)d_in[20];
    const int*   snd  = (const int*)d_in[21];
    const int*   rcv  = (const int*)d_in[22];
    float* out = (float*)d_out;

    const long E = in_sizes[21];

    short* Wb  = (short*)d_ws;
    short* nfT = Wb + W_TOTAL;
    int* cnt   = (int*)(nfT + NFT_ELEMS);
    int* off   = cnt + 2512;
    int* nxt   = off + 2512;
    int* perm  = nxt + 2512;

    // per-edge ws: perm 4B + X 4864B (Wg -> X -> Y2) + Rc 3072B (rad -> Zraw+gates)
    const size_t fixed = (size_t)W_TOTAL * 2 + (size_t)NFT_ELEMS * 2 + 3 * 2512 * 4;
    long cap = (ws_size > fixed) ? (long)((ws_size - fixed) / 7940) : 64;
    long chunk = (cap / 64) * 64;
    if (chunk < 64) chunk = 64;
    long Epad = ((E + 63) / 64) * 64;
    if (chunk > Epad) chunk = Epad;

    short* Xc = (short*)(perm + chunk);     // chunk*2432
    short* Rc = Xc + chunk * 2432;          // chunk*1536

    hipMemsetAsync(d_out, 0, (size_t)out_size * sizeof(float), stream);
    k_prep<<<(int)((W_TOTAL + 511) / 512), 512, 0, stream>>>(
        w1m0, w1r1, w1i1, w1r2, w1i2, w2m0, w2r1, w2i1, w2r2, w2i2, rw2, Wb);
    k_nft<<<NNODES, 256, 0, stream>>>(nf, nfT);

    for (long base = 0; base < E; base += chunk) {
        long n = E - base; if (n > chunk) n = chunk;
        int nb  = (int)((n + 63) / 64);
        int nbe = (int)((n + 255) / 256);

        hipMemsetAsync(cnt, 0, NNODES * sizeof(int), stream);
        k_hist<<<nbe, 256, 0, stream>>>(rcv, cnt, base, n);
        k_scan<<<1, 256, 0, stream>>>(cnt, off, nxt);
        k_scat<<<nbe, 256, 0, stream>>>(rcv, nxt, perm, base, n);

        k_rad  <<<nb * 2, 512, 0, stream>>>(ee, rw1, rb1, rb2, Wb + OFF_RW2T, Rc, base, E);
        k_wig  <<<(int)((n + 7) / 8), 256, 0, stream>>>(wig, Xc, base, n);
        k_rot2 <<<nb * 16, 256, 0, stream>>>(nfT, Rc, snd, rcv, Xc, base, n);
        k_conv1<<<dim3(nb, 3), 512, 0, stream>>>(Xc, Wb + OFF_W1T, Wb + OFF_W1C1, Wb + OFF_W1C2, b1m0, Rc);
        k_conv2<<<dim3(nb, 3), 512, 0, stream>>>(Rc, Wb + OFF_V0T, Wb + OFF_V1C, Wb + OFF_V2C, b2m0, Xc);
        k_invn <<<NNODES, 256, 0, stream>>>(Xc, winv, env, cnt, off, perm, out, base);
    }
    (void)n_in;
}